// Round 1
// baseline (1029.159 us; speedup 1.0000x reference)
//
#include <hip/hip_runtime.h>
#include <math.h>

static const int NT = 50000, NDAT = 20000, NDEV = 4;
static const int EDT = 800000, EVT = 200000, ETT = 400000;

// ---------------- workspace layout (float offsets) ----------------
static const size_t OFF_TASKS = 0;                  // 50000*256
static const size_t OFF_DEN1  = 12800000;           // 200000
static const size_t OFF_DEN2  = 13000000;           // 200000
static const size_t OFF_DEN3  = 13200000;           // 200000
static const size_t OFF_ASUM  = 13400000;           // 200000
static const size_t OFF_CNT   = 13600000;           // 50000
static const size_t ZERO_N    = 13650000;           // everything above zeroed each launch
static const size_t OFF_HS    = 13650000;           // 6,400,000 (hs1 uses 2.56M, later hs3 full)
static const size_t OFF_HS2   = 20050000;           // 512
static const size_t OFF_AS2   = 20050512;           // 16
static const size_t OFF_QS1   = 20050528;           // 32
static const size_t OFF_QD1   = 20050560;           // 64
static const size_t OFF_P1    = 20050624;           // 32
static const size_t OFF_QS2   = 20050656;           // 32
static const size_t OFF_QD2   = 20050688;           // 64
static const size_t OFF_P2    = 20050752;           // 24
static const size_t OFF_P3    = 20050776;           // 16
static const size_t OFF_EX1   = 20050792;           // 3,200,000 (reused: ex3 1.6M + exl 0.2M)
static const size_t OFF_EX2   = 23250792;           // 800,000
static const size_t OFF_AS1   = 24050792;           // 80,000
static const size_t OFF_AD1   = 24130792;           // 200,000
static const size_t OFF_AD2   = 24330792;           // 200,000
static const size_t OFF_AS3   = 24530792;           // 200,000
static const size_t OFF_AD3   = 24730792;           // 200,000
static const size_t WS_TOTAL  = 24930792;           // floats (~95 MiB)

__device__ __forceinline__ void atomAdd(float* p, float v) { unsafeAtomicAdd(p, v); }
__device__ __forceinline__ float lrelu(float a) { return a > 0.f ? a : 0.2f * a; }

// Q[k][h] = sum_c W[k*128 + h*32 + c] * A[h*32 + c], for all 7 small matrices
__global__ void k_proj_small(const float* Ws1, const float* As1,
                             const float* Wd1, const float* Ad1,
                             const float* We1, const float* Ae1,
                             const float* Ws2, const float* As2,
                             const float* Wd2, const float* Ad2,
                             const float* We2, const float* Ae2,
                             const float* We3, const float* Ae3,
                             float* Qs1, float* Qd1, float* P1,
                             float* Qs2, float* Qd2, float* P2, float* P3) {
    int t = threadIdx.x;
    const float *W, *A; float* O; int u;
    if      (t < 32)  { W = Ws1; A = As1; O = Qs1; u = t; }
    else if (t < 96)  { W = Wd1; A = Ad1; O = Qd1; u = t - 32; }
    else if (t < 128) { W = We1; A = Ae1; O = P1;  u = t - 96; }
    else if (t < 160) { W = Ws2; A = As2; O = Qs2; u = t - 128; }
    else if (t < 224) { W = Wd2; A = Ad2; O = Qd2; u = t - 160; }
    else if (t < 248) { W = We2; A = Ae2; O = P2;  u = t - 224; }
    else if (t < 264) { W = We3; A = Ae3; O = P3;  u = t - 248; }
    else return;
    int k = u >> 2, h = u & 3;
    float acc = 0.f;
    for (int c = 0; c < 32; ++c) acc += W[k * 128 + h * 32 + c] * A[h * 32 + c];
    O[k * 4 + h] = acc;
}

// out[n][j] = sum_k x[n*K+k] * W[k*128+j]   (N*128 threads)
__global__ void k_linproj(const float* __restrict__ x, const float* __restrict__ W,
                          float* __restrict__ out, int N, int K) {
    int idx = blockIdx.x * blockDim.x + threadIdx.x;
    if (idx >= N * 128) return;
    int n = idx >> 7, j = idx & 127;
    float acc = 0.f;
    for (int k = 0; k < K; ++k) acc += x[n * K + k] * W[k * 128 + j];
    out[idx] = acc;
}

// out[n][h] = sum_k x[n*K+k] * Q[k*4+h]   (N*4 threads)
__global__ void k_alpha(const float* __restrict__ x, const float* __restrict__ Q,
                        float* __restrict__ out, int N, int K) {
    int idx = blockIdx.x * blockDim.x + threadIdx.x;
    if (idx >= N * 4) return;
    int n = idx >> 2, h = idx & 3;
    float acc = 0.f;
    for (int k = 0; k < K; ++k) acc += x[n * K + k] * Q[k * 4 + h];
    out[idx] = acc;
}

// out[n][h] = sum_c hs[n*128 + h*32 + c] * A[h*32+c]
__global__ void k_alpha_from_h(const float* __restrict__ hs, const float* __restrict__ A,
                               float* __restrict__ out, int N) {
    int idx = blockIdx.x * blockDim.x + threadIdx.x;
    if (idx >= N * 4) return;
    int n = idx >> 2, h = idx & 3;
    float acc = 0.f;
    #pragma unroll
    for (int c = 0; c < 32; ++c) acc += hs[n * 128 + h * 32 + c] * A[h * 32 + c];
    out[idx] = acc;
}

// per-edge: ex = exp(leaky(as[s]+ad[d]+ea@P)); den[d] += ex
__global__ void k_edge1(const int* __restrict__ src, const int* __restrict__ dst,
                        const float* __restrict__ ea, int E, int KE,
                        const float* __restrict__ P, const float* __restrict__ as_,
                        const float* __restrict__ ad_, float* __restrict__ ex,
                        float* __restrict__ den) {
    int e = blockIdx.x * blockDim.x + threadIdx.x;
    if (e >= E) return;
    int s = src[e], d = dst[e];
    float al[4];
    #pragma unroll
    for (int h = 0; h < 4; ++h) al[h] = as_[s * 4 + h] + ad_[d * 4 + h];
    for (int k = 0; k < KE; ++k) {
        float v = ea[e * KE + k];
        #pragma unroll
        for (int h = 0; h < 4; ++h) al[h] += v * P[k * 4 + h];
    }
    #pragma unroll
    for (int h = 0; h < 4; ++h) {
        float x = expf(lrelu(al[h]));
        ex[e * 4 + h] = x;
        atomAdd(&den[d * 4 + h], x);
    }
}

// conv3 edge pass1: also accumulate asum (for self-loop mean edge attr) and cnt
__global__ void k_edge1_c3(const int* __restrict__ src, const int* __restrict__ dst,
                           const float* __restrict__ ea, const float* __restrict__ P,
                           const float* __restrict__ as_, const float* __restrict__ ad_,
                           float* __restrict__ ex, float* __restrict__ den,
                           float* __restrict__ asum, float* __restrict__ cnt) {
    int e = blockIdx.x * blockDim.x + threadIdx.x;
    if (e >= ETT) return;
    int s = src[e], d = dst[e];
    float ae[4] = {0.f, 0.f, 0.f, 0.f};
    #pragma unroll
    for (int k = 0; k < 4; ++k) {
        float v = ea[e * 4 + k];
        #pragma unroll
        for (int h = 0; h < 4; ++h) ae[h] += v * P[k * 4 + h];
    }
    #pragma unroll
    for (int h = 0; h < 4; ++h) {
        atomAdd(&asum[d * 4 + h], ae[h]);
        float x = expf(lrelu(as_[s * 4 + h] + ad_[d * 4 + h] + ae[h]));
        ex[e * 4 + h] = x;
        atomAdd(&den[d * 4 + h], x);
    }
    atomAdd(&cnt[d], 1.0f);
}

// conv3 self-loop logits: exl = exp(leaky(as+ad+asum/max(cnt,1))); den += exl
__global__ void k_loop_c3(const float* __restrict__ as_, const float* __restrict__ ad_,
                          const float* __restrict__ asum, const float* __restrict__ cnt,
                          float* __restrict__ exl, float* __restrict__ den) {
    int idx = blockIdx.x * blockDim.x + threadIdx.x;
    if (idx >= NT * 4) return;
    int n = idx >> 2;
    float m = asum[idx] / fmaxf(cnt[n], 1.0f);
    float x = expf(lrelu(as_[idx] + ad_[idx] + m));
    exl[idx] = x;
    den[idx] += x;
}

// conv1/2 weighted scatter (concat heads): one wave (64 lanes) per edge, 2 channels/lane
__global__ void k_edge2_cat(const int* __restrict__ src, const int* __restrict__ dst, int E,
                            const float* __restrict__ hs, const float* __restrict__ ex,
                            const float* __restrict__ den, float* __restrict__ tasks,
                            int cbase) {
    int t = blockIdx.x * blockDim.x + threadIdx.x;
    int e = t >> 6, lane = t & 63;
    if (e >= E) return;
    int s = src[e], d = dst[e];
    #pragma unroll
    for (int p = 0; p < 2; ++p) {
        int j = lane + 64 * p;
        int h = j >> 5;
        float w = ex[e * 4 + h] / (den[d * 4 + h] + 1e-16f);
        atomAdd(&tasks[(size_t)d * 256 + cbase + j], hs[s * 128 + j] * w);
    }
}

// conv3 weighted scatter (mean over heads): 32 lanes per edge, fold h in registers
__global__ void k_edge2_c3(const int* __restrict__ src, const int* __restrict__ dst,
                           const float* __restrict__ hs, const float* __restrict__ ex,
                           const float* __restrict__ den, float* __restrict__ out) {
    int t = blockIdx.x * blockDim.x + threadIdx.x;
    int e = t >> 5, c = t & 31;
    if (e >= ETT) return;
    int s = src[e], d = dst[e];
    float acc = 0.f;
    #pragma unroll
    for (int h = 0; h < 4; ++h)
        acc += hs[s * 128 + h * 32 + c] * (ex[e * 4 + h] / (den[d * 4 + h] + 1e-16f));
    atomAdd(&out[d * 32 + c], acc);
}

// bias+relu over tasks [NT,256]
__global__ void k_bias_relu(float* __restrict__ tasks, const float* __restrict__ b1,
                            const float* __restrict__ b2) {
    int idx = blockIdx.x * blockDim.x + threadIdx.x;
    if (idx >= NT * 256) return;
    int j = idx & 255;
    float b = (j < 128) ? b1[j] : b2[j - 128];
    float v = tasks[idx] + b;
    tasks[idx] = v > 0.f ? v : 0.f;
}

// final: add self-loop message, mean over heads, +b3, relu
__global__ void k_final(float* __restrict__ out, const float* __restrict__ hs,
                        const float* __restrict__ exl, const float* __restrict__ den,
                        const float* __restrict__ b3) {
    int idx = blockIdx.x * blockDim.x + threadIdx.x;
    if (idx >= NT * 32) return;
    int n = idx >> 5, c = idx & 31;
    float acc = out[idx];
    #pragma unroll
    for (int h = 0; h < 4; ++h)
        acc += hs[n * 128 + h * 32 + c] * (exl[n * 4 + h] / (den[n * 4 + h] + 1e-16f));
    float r = acc * 0.25f + b3[c];
    out[idx] = r > 0.f ? r : 0.f;
}

// hs3 = tasks[50000,256] @ W3[256,128]; fp32, LDS-tiled, 4x4 register blocking
__global__ __launch_bounds__(128) void k_gemm(const float* __restrict__ T,
                                              const float* __restrict__ W,
                                              float* __restrict__ out) {
    __shared__ float sW[64][128];
    __shared__ float sTt[64][16];   // transposed: sTt[k][r]
    int tid = threadIdx.x;
    int tc = tid & 31, tr = tid >> 5;          // 32 col-groups x 4 row-groups
    int r0 = blockIdx.x * 16;
    float acc[4][4] = {};
    for (int kt = 0; kt < 256; kt += 64) {
        const float4* Wg = reinterpret_cast<const float4*>(W + (size_t)kt * 128);
        float4* sW4 = reinterpret_cast<float4*>(&sW[0][0]);
        #pragma unroll
        for (int i = 0; i < 16; ++i) sW4[i * 128 + tid] = Wg[i * 128 + tid];
        #pragma unroll
        for (int i = 0; i < 2; ++i) {
            int s = i * 128 + tid;             // 0..255
            int r = s >> 4, k4 = s & 15;
            float4 v = *reinterpret_cast<const float4*>(&T[(size_t)(r0 + r) * 256 + kt + k4 * 4]);
            sTt[k4 * 4 + 0][r] = v.x; sTt[k4 * 4 + 1][r] = v.y;
            sTt[k4 * 4 + 2][r] = v.z; sTt[k4 * 4 + 3][r] = v.w;
        }
        __syncthreads();
        #pragma unroll 4
        for (int k = 0; k < 64; ++k) {
            float4 b4 = *reinterpret_cast<const float4*>(&sW[k][tc * 4]);
            float4 a4 = *reinterpret_cast<const float4*>(&sTt[k][tr * 4]);
            float av[4] = {a4.x, a4.y, a4.z, a4.w};
            float bv[4] = {b4.x, b4.y, b4.z, b4.w};
            #pragma unroll
            for (int r = 0; r < 4; ++r)
                #pragma unroll
                for (int c = 0; c < 4; ++c) acc[r][c] += av[r] * bv[c];
        }
        __syncthreads();
    }
    #pragma unroll
    for (int r = 0; r < 4; ++r) {
        float4 o = make_float4(acc[r][0], acc[r][1], acc[r][2], acc[r][3]);
        *reinterpret_cast<float4*>(&out[(size_t)(r0 + tr * 4 + r) * 128 + tc * 4]) = o;
    }
}

extern "C" void kernel_launch(void* const* d_in, const int* in_sizes, int n_in,
                              void* d_out, int out_size, void* d_ws, size_t ws_size,
                              hipStream_t stream) {
    const float* x_data  = (const float*)d_in[0];
    const float* x_tasks = (const float*)d_in[1];
    const float* x_dev   = (const float*)d_in[2];
    const int*   ei_dt   = (const int*)d_in[3];
    const float* ea_dt   = (const float*)d_in[4];
    const int*   ei_vt   = (const int*)d_in[5];
    const float* ea_vt   = (const float*)d_in[6];
    const int*   ei_tt   = (const int*)d_in[7];
    const float* ea_tt   = (const float*)d_in[8];
    const float* Ws1 = (const float*)d_in[9];  const float* Wd1 = (const float*)d_in[10];
    const float* We1 = (const float*)d_in[11]; const float* As1 = (const float*)d_in[12];
    const float* Ad1 = (const float*)d_in[13]; const float* Ae1 = (const float*)d_in[14];
    const float* b1  = (const float*)d_in[15];
    const float* Ws2 = (const float*)d_in[16]; const float* Wd2 = (const float*)d_in[17];
    const float* We2 = (const float*)d_in[18]; const float* As2 = (const float*)d_in[19];
    const float* Ad2 = (const float*)d_in[20]; const float* Ae2 = (const float*)d_in[21];
    const float* b2  = (const float*)d_in[22];
    const float* W3  = (const float*)d_in[23]; const float* We3 = (const float*)d_in[24];
    const float* As3 = (const float*)d_in[25]; const float* Ad3 = (const float*)d_in[26];
    const float* Ae3 = (const float*)d_in[27]; const float* b3  = (const float*)d_in[28];

    if (ws_size < WS_TOTAL * sizeof(float)) return;  // workspace too small: bail

    float* w = (float*)d_ws;
    float* tasks = w + OFF_TASKS;
    float* den1 = w + OFF_DEN1; float* den2 = w + OFF_DEN2; float* den3 = w + OFF_DEN3;
    float* asum = w + OFF_ASUM; float* cnt = w + OFF_CNT;
    float* hs   = w + OFF_HS;      // hs1 then hs3
    float* hs2  = w + OFF_HS2;  float* as2 = w + OFF_AS2;
    float* Qs1 = w + OFF_QS1; float* Qd1 = w + OFF_QD1; float* P1 = w + OFF_P1;
    float* Qs2 = w + OFF_QS2; float* Qd2 = w + OFF_QD2; float* P2 = w + OFF_P2;
    float* P3  = w + OFF_P3;
    float* ex1 = w + OFF_EX1; float* ex2 = w + OFF_EX2;
    float* ex3 = w + OFF_EX1;                 // reuse (conv1 done)
    float* exl = w + OFF_EX1 + 1600000;
    float* as1 = w + OFF_AS1; float* ad1 = w + OFF_AD1; float* ad2 = w + OFF_AD2;
    float* as3 = w + OFF_AS3; float* ad3 = w + OFF_AD3;
    float* out = (float*)d_out;

    dim3 B(256);
    #define GRID(n) dim3((unsigned)(((n) + 255) / 256))

    hipMemsetAsync(w, 0, ZERO_N * sizeof(float), stream);
    hipMemsetAsync(d_out, 0, (size_t)out_size * sizeof(float), stream);

    k_proj_small<<<1, 320, 0, stream>>>(Ws1, As1, Wd1, Ad1, We1, Ae1,
                                        Ws2, As2, Wd2, Ad2, We2, Ae2, We3, Ae3,
                                        Qs1, Qd1, P1, Qs2, Qd2, P2, P3);
    // conv1: data -> tasks
    k_linproj<<<GRID(NDAT * 128), B, 0, stream>>>(x_data, Ws1, hs, NDAT, 8);
    k_alpha<<<GRID(NDAT * 4), B, 0, stream>>>(x_data, Qs1, as1, NDAT, 8);
    k_alpha<<<GRID(NT * 4), B, 0, stream>>>(x_tasks, Qd1, ad1, NT, 16);
    k_edge1<<<GRID(EDT), B, 0, stream>>>(ei_dt, ei_dt + EDT, ea_dt, EDT, 8, P1, as1, ad1, ex1, den1);
    k_edge2_cat<<<GRID((size_t)EDT * 64), B, 0, stream>>>(ei_dt, ei_dt + EDT, EDT, hs, ex1, den1, tasks, 0);
    // conv2: dev -> tasks
    k_linproj<<<GRID(NDEV * 128), B, 0, stream>>>(x_dev, Ws2, hs2, NDEV, 8);
    k_alpha<<<GRID(NDEV * 4), B, 0, stream>>>(x_dev, Qs2, as2, NDEV, 8);
    k_alpha<<<GRID(NT * 4), B, 0, stream>>>(x_tasks, Qd2, ad2, NT, 16);
    k_edge1<<<GRID(EVT), B, 0, stream>>>(ei_vt, ei_vt + EVT, ea_vt, EVT, 6, P2, as2, ad2, ex2, den2);
    k_edge2_cat<<<GRID((size_t)EVT * 64), B, 0, stream>>>(ei_vt, ei_vt + EVT, EVT, hs2, ex2, den2, tasks, 128);
    // bias+relu on concatenated tasks
    k_bias_relu<<<GRID(NT * 256), B, 0, stream>>>(tasks, b1, b2);
    // conv3: tasks -> tasks (self loops, mean heads)
    k_gemm<<<dim3(NT / 16), dim3(128), 0, stream>>>(tasks, W3, hs);
    k_alpha_from_h<<<GRID(NT * 4), B, 0, stream>>>(hs, As3, as3, NT);
    k_alpha_from_h<<<GRID(NT * 4), B, 0, stream>>>(hs, Ad3, ad3, NT);
    k_edge1_c3<<<GRID(ETT), B, 0, stream>>>(ei_tt, ei_tt + ETT, ea_tt, P3, as3, ad3, ex3, den3, asum, cnt);
    k_loop_c3<<<GRID(NT * 4), B, 0, stream>>>(as3, ad3, asum, cnt, exl, den3);
    k_edge2_c3<<<GRID((size_t)ETT * 32), B, 0, stream>>>(ei_tt, ei_tt + ETT, hs, ex3, den3, out);
    k_final<<<GRID(NT * 32), B, 0, stream>>>(out, hs, exl, den3, b3);
    #undef GRID
}

// Round 2
// 582.102 us; speedup vs baseline: 1.7680x; 1.7680x over previous
//
#include <hip/hip_runtime.h>
#include <math.h>

static const int NT = 50000, NDAT = 20000, NDEV = 4;
static const int EDT = 800000, EVT = 200000, ETT = 400000;

// ---------------- workspace layout (float offsets), liveness-aliased ----------------
static const size_t OFF_TASKS = 0;                   // 12,800,000  [NT,256] fp32
static const size_t OFF_HS    = 12800000;            //  6,400,000  hs1 (2.56M) then hs3 (6.4M)
static const size_t OFF_ESRC1 = OFF_HS + 2560000;    //    800,000  ints (dead before gemm writes hs3)
static const size_t OFF_ESRC2 = OFF_HS + 3360000;    //    200,000  ints (dead before gemm)
static const size_t OFF_WV1   = 19200000;            //  3,200,000  conv1 ex4/slot; wv3 (8/slot) reuses
static const size_t OFF_WV2   = 22400000;            //    800,000  conv2 ex4/slot; esrc3 reuses
static const size_t OFF_DEG   = 23200000;            //    150,000  3 x NT ints; becomes bucket cursor
static const size_t OFF_RP    = 23350000;            //    150,003  3 x (NT+1) ints
static const size_t OFF_AS1   = 23500004;            //     80,000
static const size_t OFF_AD1   = 23580004;            //    200,000  as3 reuses
static const size_t OFF_AD2   = 23780004;            //    200,000  ad3 reuses
static const size_t OFF_HS2   = 23980004;            //        512
static const size_t OFF_AS2   = 23980516;            //         16
static const size_t OFF_QS1   = 23980532;            //         32
static const size_t OFF_QD1   = 23980564;            //         64
static const size_t OFF_P1    = 23980628;            //         32
static const size_t OFF_QS2   = 23980660;            //         32
static const size_t OFF_QD2   = 23980692;            //         64
static const size_t OFF_P2    = 23980756;            //         24
static const size_t OFF_P3    = 23980780;            //         16
static const size_t WS_TOTAL  = 23980796;            // floats (~96 MiB, <= round-1's accepted 24.93M)

__device__ __forceinline__ float lrelu(float a) { return a > 0.f ? a : 0.2f * a; }

// Q[k][h] = sum_c W[k*128 + h*32 + c] * A[h*32 + c], for all 7 small matrices
__global__ void k_proj_small(const float* Ws1, const float* As1,
                             const float* Wd1, const float* Ad1,
                             const float* We1, const float* Ae1,
                             const float* Ws2, const float* As2,
                             const float* Wd2, const float* Ad2,
                             const float* We2, const float* Ae2,
                             const float* We3, const float* Ae3,
                             float* Qs1, float* Qd1, float* P1,
                             float* Qs2, float* Qd2, float* P2, float* P3) {
    int t = threadIdx.x;
    const float *W, *A; float* O; int u;
    if      (t < 32)  { W = Ws1; A = As1; O = Qs1; u = t; }
    else if (t < 96)  { W = Wd1; A = Ad1; O = Qd1; u = t - 32; }
    else if (t < 128) { W = We1; A = Ae1; O = P1;  u = t - 96; }
    else if (t < 160) { W = Ws2; A = As2; O = Qs2; u = t - 128; }
    else if (t < 224) { W = Wd2; A = Ad2; O = Qd2; u = t - 160; }
    else if (t < 248) { W = We2; A = Ae2; O = P2;  u = t - 224; }
    else if (t < 264) { W = We3; A = Ae3; O = P3;  u = t - 248; }
    else return;
    int k = u >> 2, h = u & 3;
    float acc = 0.f;
    for (int c = 0; c < 32; ++c) acc += W[k * 128 + h * 32 + c] * A[h * 32 + c];
    O[k * 4 + h] = acc;
}

// out[n][j] = sum_k x[n*K+k] * W[k*128+j]
__global__ void k_linproj(const float* __restrict__ x, const float* __restrict__ W,
                          float* __restrict__ out, int N, int K) {
    int idx = blockIdx.x * blockDim.x + threadIdx.x;
    if (idx >= N * 128) return;
    int n = idx >> 7, j = idx & 127;
    float acc = 0.f;
    for (int k = 0; k < K; ++k) acc += x[n * K + k] * W[k * 128 + j];
    out[idx] = acc;
}

// out[n][h] = sum_k x[n*K+k] * Q[k*4+h]
__global__ void k_alpha(const float* __restrict__ x, const float* __restrict__ Q,
                        float* __restrict__ out, int N, int K) {
    int idx = blockIdx.x * blockDim.x + threadIdx.x;
    if (idx >= N * 4) return;
    int n = idx >> 2, h = idx & 3;
    float acc = 0.f;
    for (int k = 0; k < K; ++k) acc += x[n * K + k] * Q[k * 4 + h];
    out[idx] = acc;
}

// out[n][h] = sum_c hs[n*128 + h*32 + c] * A[h*32+c]
__global__ void k_alpha_from_h(const float* __restrict__ hs, const float* __restrict__ A,
                               float* __restrict__ out, int N) {
    int idx = blockIdx.x * blockDim.x + threadIdx.x;
    if (idx >= N * 4) return;
    int n = idx >> 2, h = idx & 3;
    float acc = 0.f;
    #pragma unroll
    for (int c = 0; c < 32; ++c) acc += hs[n * 128 + h * 32 + c] * A[h * 32 + c];
    out[idx] = acc;
}

// degree histogram for all 3 graphs in one grid
__global__ void k_hist(const int* __restrict__ dt, const int* __restrict__ vt,
                       const int* __restrict__ tt, int* __restrict__ deg) {
    int e = blockIdx.x * blockDim.x + threadIdx.x;
    if (e < EDT) atomicAdd(&deg[dt[EDT + e]], 1);
    else if (e < EDT + EVT) atomicAdd(&deg[NT + vt[EVT + (e - EDT)]], 1);
    else if (e < EDT + EVT + ETT) atomicAdd(&deg[2 * NT + tt[ETT + (e - EDT - EVT)]], 1);
}

// per-graph exclusive scan: block g scans deg[g*NT..] -> rp[g*(NT+1)..]; leaves cursor copy in deg
__global__ __launch_bounds__(1024) void k_scan(int* __restrict__ deg, int* __restrict__ rp) {
    const int CH = 49;  // 1024*49 = 50176 >= NT
    __shared__ int sums[1024];
    int g = blockIdx.x;
    int* dg = deg + (size_t)g * NT;
    int* rpg = rp + (size_t)g * (NT + 1);
    int t = threadIdx.x;
    int base = t * CH;
    int v[CH];
    int s = 0;
    #pragma unroll
    for (int i = 0; i < CH; ++i) {
        int idx = base + i;
        int x = (idx < NT) ? dg[idx] : 0;
        v[i] = x; s += x;
    }
    sums[t] = s;
    __syncthreads();
    for (int off = 1; off < 1024; off <<= 1) {
        int x = (t >= off) ? sums[t - off] : 0;
        __syncthreads();
        sums[t] += x;
        __syncthreads();
    }
    int run = (t == 0) ? 0 : sums[t - 1];
    #pragma unroll
    for (int i = 0; i < CH; ++i) {
        int idx = base + i;
        if (idx < NT) { rpg[idx] = run; dg[idx] = run; run += v[i]; }
    }
    if (t == 1023) rpg[NT] = sums[1023];
}

// fused: per-edge attention exp + bucket into CSR slots (conv1/conv2)
__global__ void k_edge_bucket(const int* __restrict__ src, const int* __restrict__ dst,
                              const float* __restrict__ ea, int E, int KE,
                              const float* __restrict__ P, const float* __restrict__ as_,
                              const float* __restrict__ ad_,
                              int* __restrict__ cur, int* __restrict__ esrc,
                              float* __restrict__ wv) {
    int e = blockIdx.x * blockDim.x + threadIdx.x;
    if (e >= E) return;
    int s = src[e], d = dst[e];
    float al[4];
    #pragma unroll
    for (int h = 0; h < 4; ++h) al[h] = as_[s * 4 + h] + ad_[d * 4 + h];
    for (int k = 0; k < KE; ++k) {
        float v = ea[e * KE + k];
        #pragma unroll
        for (int h = 0; h < 4; ++h) al[h] += v * P[k * 4 + h];
    }
    int slot = atomicAdd(&cur[d], 1);
    esrc[slot] = s;
    float4 w4 = make_float4(expf(lrelu(al[0])), expf(lrelu(al[1])),
                            expf(lrelu(al[2])), expf(lrelu(al[3])));
    *reinterpret_cast<float4*>(&wv[(size_t)slot * 4]) = w4;
}

// conv3 variant: also stores the edge-attr logit part ae (needed for self-loop mean)
__global__ void k_edge_bucket_c3(const int* __restrict__ src, const int* __restrict__ dst,
                                 const float* __restrict__ ea, const float* __restrict__ P,
                                 const float* __restrict__ as_, const float* __restrict__ ad_,
                                 int* __restrict__ cur, int* __restrict__ esrc,
                                 float* __restrict__ wv) {
    int e = blockIdx.x * blockDim.x + threadIdx.x;
    if (e >= ETT) return;
    int s = src[e], d = dst[e];
    float ae[4] = {0.f, 0.f, 0.f, 0.f};
    #pragma unroll
    for (int k = 0; k < 4; ++k) {
        float v = ea[e * 4 + k];
        #pragma unroll
        for (int h = 0; h < 4; ++h) ae[h] += v * P[k * 4 + h];
    }
    int slot = atomicAdd(&cur[d], 1);
    esrc[slot] = s;
    float4 x4 = make_float4(expf(lrelu(as_[s * 4 + 0] + ad_[d * 4 + 0] + ae[0])),
                            expf(lrelu(as_[s * 4 + 1] + ad_[d * 4 + 1] + ae[1])),
                            expf(lrelu(as_[s * 4 + 2] + ad_[d * 4 + 2] + ae[2])),
                            expf(lrelu(as_[s * 4 + 3] + ad_[d * 4 + 3] + ae[3])));
    *reinterpret_cast<float4*>(&wv[(size_t)slot * 8]) = x4;
    *reinterpret_cast<float4*>(&wv[(size_t)slot * 8 + 4]) = make_float4(ae[0], ae[1], ae[2], ae[3]);
}

// CSR gather for conv1/conv2: 128 threads per dst (2 dst/block); common-denominator softmax
// epilogue folds +bias and relu, writes tasks[:, cbase:cbase+128] exactly once.
__global__ __launch_bounds__(256) void k_gather12(const int* __restrict__ rp,
                                                  const int* __restrict__ esrc,
                                                  const float* __restrict__ wv,
                                                  const float* __restrict__ hs,
                                                  const float* __restrict__ bias,
                                                  float* __restrict__ tasks, int cbase) {
    int tid = threadIdx.x;
    int d = blockIdx.x * 2 + (tid >> 7);
    int j = tid & 127;
    int h = j >> 5;
    int i1 = rp[d + 1];
    float acc = 0.f, den = 0.f;
    for (int i = rp[d]; i < i1; ++i) {
        int s = esrc[i];
        float w = wv[(size_t)i * 4 + h];
        acc += hs[(size_t)s * 128 + j] * w;
        den += w;
    }
    float v = acc / (den + 1e-16f) + bias[j];
    tasks[(size_t)d * 256 + cbase + j] = v > 0.f ? v : 0.f;
}

// CSR gather for conv3: 32 threads per dst (8 dst/block); per-head softmax denominators,
// self-loop (mean edge-attr) message, head-mean, +b3, relu — all fused. Writes d_out once.
__global__ __launch_bounds__(256) void k_gather_c3(const int* __restrict__ rp,
                                                   const int* __restrict__ esrc,
                                                   const float* __restrict__ wv,
                                                   const float* __restrict__ hs,
                                                   const float* __restrict__ as3,
                                                   const float* __restrict__ ad3,
                                                   const float* __restrict__ b3,
                                                   float* __restrict__ out) {
    int tid = threadIdx.x;
    int d = blockIdx.x * 8 + (tid >> 5);
    int c = tid & 31;
    int i0 = rp[d], i1 = rp[d + 1];
    float acc[4] = {0.f, 0.f, 0.f, 0.f};
    float den[4] = {0.f, 0.f, 0.f, 0.f};
    float aes[4] = {0.f, 0.f, 0.f, 0.f};
    for (int i = i0; i < i1; ++i) {
        int s = esrc[i];
        float4 x4 = *reinterpret_cast<const float4*>(&wv[(size_t)i * 8]);
        float4 a4 = *reinterpret_cast<const float4*>(&wv[(size_t)i * 8 + 4]);
        const float* hrow = hs + (size_t)s * 128 + c;
        acc[0] += x4.x * hrow[0];  acc[1] += x4.y * hrow[32];
        acc[2] += x4.z * hrow[64]; acc[3] += x4.w * hrow[96];
        den[0] += x4.x; den[1] += x4.y; den[2] += x4.z; den[3] += x4.w;
        aes[0] += a4.x; aes[1] += a4.y; aes[2] += a4.z; aes[3] += a4.w;
    }
    float inv = 1.f / fmaxf((float)(i1 - i0), 1.f);
    const float* hd = hs + (size_t)d * 128 + c;
    float o = 0.f;
    #pragma unroll
    for (int h = 0; h < 4; ++h) {
        float m = aes[h] * inv;
        float exl = expf(lrelu(as3[d * 4 + h] + ad3[d * 4 + h] + m));
        float a = acc[h] + exl * hd[h * 32];
        o += a / (den[h] + exl + 1e-16f);
    }
    o = 0.25f * o + b3[c];
    out[(size_t)d * 32 + c] = o > 0.f ? o : 0.f;
}

// hs3 = tasks[50000,256] @ W3[256,128]; fp32, LDS-tiled, 4x4 register blocking
__global__ __launch_bounds__(128) void k_gemm(const float* __restrict__ T,
                                              const float* __restrict__ W,
                                              float* __restrict__ out) {
    __shared__ float sW[64][128];
    __shared__ float sTt[64][16];   // transposed: sTt[k][r]
    int tid = threadIdx.x;
    int tc = tid & 31, tr = tid >> 5;
    int r0 = blockIdx.x * 16;
    float acc[4][4] = {};
    for (int kt = 0; kt < 256; kt += 64) {
        const float4* Wg = reinterpret_cast<const float4*>(W + (size_t)kt * 128);
        float4* sW4 = reinterpret_cast<float4*>(&sW[0][0]);
        #pragma unroll
        for (int i = 0; i < 16; ++i) sW4[i * 128 + tid] = Wg[i * 128 + tid];
        #pragma unroll
        for (int i = 0; i < 2; ++i) {
            int s = i * 128 + tid;
            int r = s >> 4, k4 = s & 15;
            float4 v = *reinterpret_cast<const float4*>(&T[(size_t)(r0 + r) * 256 + kt + k4 * 4]);
            sTt[k4 * 4 + 0][r] = v.x; sTt[k4 * 4 + 1][r] = v.y;
            sTt[k4 * 4 + 2][r] = v.z; sTt[k4 * 4 + 3][r] = v.w;
        }
        __syncthreads();
        #pragma unroll 4
        for (int k = 0; k < 64; ++k) {
            float4 b4 = *reinterpret_cast<const float4*>(&sW[k][tc * 4]);
            float4 a4 = *reinterpret_cast<const float4*>(&sTt[k][tr * 4]);
            float av[4] = {a4.x, a4.y, a4.z, a4.w};
            float bv[4] = {b4.x, b4.y, b4.z, b4.w};
            #pragma unroll
            for (int r = 0; r < 4; ++r)
                #pragma unroll
                for (int c = 0; c < 4; ++c) acc[r][c] += av[r] * bv[c];
        }
        __syncthreads();
    }
    #pragma unroll
    for (int r = 0; r < 4; ++r) {
        float4 o = make_float4(acc[r][0], acc[r][1], acc[r][2], acc[r][3]);
        *reinterpret_cast<float4*>(&out[(size_t)(r0 + tr * 4 + r) * 128 + tc * 4]) = o;
    }
}

extern "C" void kernel_launch(void* const* d_in, const int* in_sizes, int n_in,
                              void* d_out, int out_size, void* d_ws, size_t ws_size,
                              hipStream_t stream) {
    const float* x_data  = (const float*)d_in[0];
    const float* x_tasks = (const float*)d_in[1];
    const float* x_dev   = (const float*)d_in[2];
    const int*   ei_dt   = (const int*)d_in[3];
    const float* ea_dt   = (const float*)d_in[4];
    const int*   ei_vt   = (const int*)d_in[5];
    const float* ea_vt   = (const float*)d_in[6];
    const int*   ei_tt   = (const int*)d_in[7];
    const float* ea_tt   = (const float*)d_in[8];
    const float* Ws1 = (const float*)d_in[9];  const float* Wd1 = (const float*)d_in[10];
    const float* We1 = (const float*)d_in[11]; const float* As1 = (const float*)d_in[12];
    const float* Ad1 = (const float*)d_in[13]; const float* Ae1 = (const float*)d_in[14];
    const float* b1  = (const float*)d_in[15];
    const float* Ws2 = (const float*)d_in[16]; const float* Wd2 = (const float*)d_in[17];
    const float* We2 = (const float*)d_in[18]; const float* As2 = (const float*)d_in[19];
    const float* Ad2 = (const float*)d_in[20]; const float* Ae2 = (const float*)d_in[21];
    const float* b2  = (const float*)d_in[22];
    const float* W3  = (const float*)d_in[23]; const float* We3 = (const float*)d_in[24];
    const float* As3 = (const float*)d_in[25]; const float* Ad3 = (const float*)d_in[26];
    const float* Ae3 = (const float*)d_in[27]; const float* b3  = (const float*)d_in[28];

    if (ws_size < WS_TOTAL * sizeof(float)) return;

    float* w = (float*)d_ws;
    float* tasks = w + OFF_TASKS;
    float* hs    = w + OFF_HS;                 // hs1 (conv1) then hs3 (conv3)
    int*   esrc1 = (int*)(w + OFF_ESRC1);
    int*   esrc2 = (int*)(w + OFF_ESRC2);
    float* wv1   = w + OFF_WV1;
    float* wv3   = w + OFF_WV1;                // aliases wv1 (dead by conv3)
    float* wv2   = w + OFF_WV2;
    int*   esrc3 = (int*)(w + OFF_WV2);        // aliases wv2 (dead by conv3)
    int*   deg   = (int*)(w + OFF_DEG);        // also bucket cursor after scan
    int*   rp    = (int*)(w + OFF_RP);
    float* as1 = w + OFF_AS1;
    float* ad1 = w + OFF_AD1; float* as3 = w + OFF_AD1;   // as3 aliases ad1
    float* ad2 = w + OFF_AD2; float* ad3 = w + OFF_AD2;   // ad3 aliases ad2
    float* hs2 = w + OFF_HS2; float* as2 = w + OFF_AS2;
    float* Qs1 = w + OFF_QS1; float* Qd1 = w + OFF_QD1; float* P1 = w + OFF_P1;
    float* Qs2 = w + OFF_QS2; float* Qd2 = w + OFF_QD2; float* P2 = w + OFF_P2;
    float* P3  = w + OFF_P3;
    float* out = (float*)d_out;

    dim3 B(256);
    #define GRID(n) dim3((unsigned)(((n) + 255) / 256))

    // CSR prep: zero degrees, histogram, per-graph scan (writes rp + cursor copy)
    hipMemsetAsync(deg, 0, 3 * NT * sizeof(int), stream);
    k_proj_small<<<1, 320, 0, stream>>>(Ws1, As1, Wd1, Ad1, We1, Ae1,
                                        Ws2, As2, Wd2, Ad2, We2, Ae2, We3, Ae3,
                                        Qs1, Qd1, P1, Qs2, Qd2, P2, P3);
    k_hist<<<GRID(EDT + EVT + ETT), B, 0, stream>>>(ei_dt, ei_vt, ei_tt, deg);
    k_scan<<<3, 1024, 0, stream>>>(deg, rp);

    // conv1 inputs
    k_linproj<<<GRID(NDAT * 128), B, 0, stream>>>(x_data, Ws1, hs, NDAT, 8);
    k_alpha<<<GRID(NDAT * 4), B, 0, stream>>>(x_data, Qs1, as1, NDAT, 8);
    k_alpha<<<GRID(NT * 4), B, 0, stream>>>(x_tasks, Qd1, ad1, NT, 16);
    k_edge_bucket<<<GRID(EDT), B, 0, stream>>>(ei_dt, ei_dt + EDT, ea_dt, EDT, 8,
                                               P1, as1, ad1, deg, esrc1, wv1);
    // conv2 inputs
    k_linproj<<<GRID(NDEV * 128), B, 0, stream>>>(x_dev, Ws2, hs2, NDEV, 8);
    k_alpha<<<GRID(NDEV * 4), B, 0, stream>>>(x_dev, Qs2, as2, NDEV, 8);
    k_alpha<<<GRID(NT * 4), B, 0, stream>>>(x_tasks, Qd2, ad2, NT, 16);
    k_edge_bucket<<<GRID(EVT), B, 0, stream>>>(ei_vt, ei_vt + EVT, ea_vt, EVT, 6,
                                               P2, as2, ad2, deg + NT, esrc2, wv2);
    // gathers (write tasks fully, bias+relu fused)
    k_gather12<<<dim3(NT / 2), B, 0, stream>>>(rp, esrc1, wv1, hs, b1, tasks, 0);
    k_gather12<<<dim3(NT / 2), B, 0, stream>>>(rp + (NT + 1), esrc2, wv2, hs2, b2, tasks, 128);

    // conv3: tasks -> tasks
    k_gemm<<<dim3(NT / 16), dim3(128), 0, stream>>>(tasks, W3, hs);
    k_alpha_from_h<<<GRID(NT * 4), B, 0, stream>>>(hs, As3, as3, NT);
    k_alpha_from_h<<<GRID(NT * 4), B, 0, stream>>>(hs, Ad3, ad3, NT);
    k_edge_bucket_c3<<<GRID(ETT), B, 0, stream>>>(ei_tt, ei_tt + ETT, ea_tt, P3,
                                                  as3, ad3, deg + 2 * NT, esrc3, wv3);
    k_gather_c3<<<dim3(NT / 8), B, 0, stream>>>(rp + 2 * (NT + 1), esrc3, wv3, hs,
                                                as3, ad3, b3, out);
    #undef GRID
}

// Round 3
// 451.712 us; speedup vs baseline: 2.2784x; 1.2887x over previous
//
#include <hip/hip_runtime.h>
#include <math.h>

static const int NT = 50000, NDAT = 20000, NDEV = 4;
static const int EDT = 800000, EVT = 200000, ETT = 400000;

// ---------------- workspace layout (float offsets), liveness-aliased ----------------
static const size_t OFF_TASKS = 0;                   // 12,800,000  [NT,256] fp32
static const size_t OFF_HS    = 12800000;            //  6,400,000  hs1 (2.56M) then hs3 (6.4M)
static const size_t OFF_ESRC1 = OFF_HS + 2560000;    //    800,000  ints (dead before gemm writes hs3)
static const size_t OFF_ESRC2 = OFF_HS + 3360000;    //    200,000  ints (dead before gemm)
static const size_t OFF_WV1   = 19200000;            //  3,200,000  conv1 ex4/slot; wv3 (8/slot) reuses
static const size_t OFF_WV2   = 22400000;            //    800,000  conv2 ex4/slot; esrc3 reuses
static const size_t OFF_DEG   = 23200000;            //    150,000  3 x NT ints; becomes bucket cursor
static const size_t OFF_RP    = 23350000;            //    150,003  3 x (NT+1) ints
static const size_t OFF_AS1   = 23500004;            //     80,000
static const size_t OFF_AD1   = 23580004;            //    200,000  as3 reuses
static const size_t OFF_AD2   = 23780004;            //    200,000  ad3 reuses
static const size_t OFF_HS2   = 23980004;            //        512
static const size_t OFF_AS2   = 23980516;            //         16
static const size_t OFF_QS1   = 23980532;            //         32
static const size_t OFF_QD1   = 23980564;            //         64
static const size_t OFF_P1    = 23980628;            //         32
static const size_t OFF_QS2   = 23980660;            //         32
static const size_t OFF_QD2   = 23980692;            //         64
static const size_t OFF_P2    = 23980756;            //         24
static const size_t OFF_P3    = 23980780;            //         16
static const size_t WS_TOTAL  = 23980796;            // floats (~96 MiB)

__device__ __forceinline__ float lrelu(float a) { return a > 0.f ? a : 0.2f * a; }

// Q[k][h] = sum_c W[k*128 + h*32 + c] * A[h*32 + c], for all 7 small matrices
__global__ void k_proj_small(const float* Ws1, const float* As1,
                             const float* Wd1, const float* Ad1,
                             const float* We1, const float* Ae1,
                             const float* Ws2, const float* As2,
                             const float* Wd2, const float* Ad2,
                             const float* We2, const float* Ae2,
                             const float* We3, const float* Ae3,
                             float* Qs1, float* Qd1, float* P1,
                             float* Qs2, float* Qd2, float* P2, float* P3) {
    int t = threadIdx.x;
    const float *W, *A; float* O; int u;
    if      (t < 32)  { W = Ws1; A = As1; O = Qs1; u = t; }
    else if (t < 96)  { W = Wd1; A = Ad1; O = Qd1; u = t - 32; }
    else if (t < 128) { W = We1; A = Ae1; O = P1;  u = t - 96; }
    else if (t < 160) { W = Ws2; A = As2; O = Qs2; u = t - 128; }
    else if (t < 224) { W = Wd2; A = Ad2; O = Qd2; u = t - 160; }
    else if (t < 248) { W = We2; A = Ae2; O = P2;  u = t - 224; }
    else if (t < 264) { W = We3; A = Ae3; O = P3;  u = t - 248; }
    else return;
    int k = u >> 2, h = u & 3;
    float acc = 0.f;
    for (int c = 0; c < 32; ++c) acc += W[k * 128 + h * 32 + c] * A[h * 32 + c];
    O[k * 4 + h] = acc;
}

// out[n][j] = sum_k x[n*K+k] * W[k*128+j]
__global__ void k_linproj(const float* __restrict__ x, const float* __restrict__ W,
                          float* __restrict__ out, int N, int K) {
    int idx = blockIdx.x * blockDim.x + threadIdx.x;
    if (idx >= N * 128) return;
    int n = idx >> 7, j = idx & 127;
    float acc = 0.f;
    for (int k = 0; k < K; ++k) acc += x[n * K + k] * W[k * 128 + j];
    out[idx] = acc;
}

// out[n][h] = sum_k x[n*K+k] * Q[k*4+h]
__global__ void k_alpha(const float* __restrict__ x, const float* __restrict__ Q,
                        float* __restrict__ out, int N, int K) {
    int idx = blockIdx.x * blockDim.x + threadIdx.x;
    if (idx >= N * 4) return;
    int n = idx >> 2, h = idx & 3;
    float acc = 0.f;
    for (int k = 0; k < K; ++k) acc += x[n * K + k] * Q[k * 4 + h];
    out[idx] = acc;
}

// fused: adA[n][h] = x@Qa, adB[n][h] = x@Qb  (one pass over x_tasks)
__global__ void k_alpha2(const float* __restrict__ x, const float* __restrict__ Qa,
                         const float* __restrict__ Qb, float* __restrict__ oa,
                         float* __restrict__ ob, int N, int K) {
    int idx = blockIdx.x * blockDim.x + threadIdx.x;
    if (idx >= N * 4) return;
    int n = idx >> 2, h = idx & 3;
    float a = 0.f, b = 0.f;
    for (int k = 0; k < K; ++k) {
        float v = x[n * K + k];
        a += v * Qa[k * 4 + h];
        b += v * Qb[k * 4 + h];
    }
    oa[idx] = a; ob[idx] = b;
}

// fused: as3[n][h] and ad3[n][h] from one pass over hs row
__global__ void k_alpha_from_h2(const float* __restrict__ hs, const float* __restrict__ As,
                                const float* __restrict__ Ad, float* __restrict__ oa,
                                float* __restrict__ ob, int N) {
    int idx = blockIdx.x * blockDim.x + threadIdx.x;
    if (idx >= N * 4) return;
    int n = idx >> 2, h = idx & 3;
    float a = 0.f, b = 0.f;
    #pragma unroll
    for (int c = 0; c < 32; ++c) {
        float v = hs[n * 128 + h * 32 + c];
        a += v * As[h * 32 + c];
        b += v * Ad[h * 32 + c];
    }
    oa[idx] = a; ob[idx] = b;
}

// degree histogram for all 3 graphs in one grid
__global__ void k_hist(const int* __restrict__ dt, const int* __restrict__ vt,
                       const int* __restrict__ tt, int* __restrict__ deg) {
    int e = blockIdx.x * blockDim.x + threadIdx.x;
    if (e < EDT) atomicAdd(&deg[dt[EDT + e]], 1);
    else if (e < EDT + EVT) atomicAdd(&deg[NT + vt[EVT + (e - EDT)]], 1);
    else if (e < EDT + EVT + ETT) atomicAdd(&deg[2 * NT + tt[ETT + (e - EDT - EVT)]], 1);
}

// per-graph exclusive scan: block g scans deg[g*NT..] -> rp[g*(NT+1)..]; leaves cursor copy in deg
__global__ __launch_bounds__(1024) void k_scan(int* __restrict__ deg, int* __restrict__ rp) {
    const int CH = 49;  // 1024*49 = 50176 >= NT
    __shared__ int sums[1024];
    int g = blockIdx.x;
    int* dg = deg + (size_t)g * NT;
    int* rpg = rp + (size_t)g * (NT + 1);
    int t = threadIdx.x;
    int base = t * CH;
    int v[CH];
    int s = 0;
    #pragma unroll
    for (int i = 0; i < CH; ++i) {
        int idx = base + i;
        int x = (idx < NT) ? dg[idx] : 0;
        v[i] = x; s += x;
    }
    sums[t] = s;
    __syncthreads();
    for (int off = 1; off < 1024; off <<= 1) {
        int x = (t >= off) ? sums[t - off] : 0;
        __syncthreads();
        sums[t] += x;
        __syncthreads();
    }
    int run = (t == 0) ? 0 : sums[t - 1];
    #pragma unroll
    for (int i = 0; i < CH; ++i) {
        int idx = base + i;
        if (idx < NT) { rpg[idx] = run; dg[idx] = run; run += v[i]; }
    }
    if (t == 1023) rpg[NT] = sums[1023];
}

// fused: per-edge attention exp + bucket into CSR slots (conv1/conv2)
__global__ void k_edge_bucket(const int* __restrict__ src, const int* __restrict__ dst,
                              const float* __restrict__ ea, int E, int KE,
                              const float* __restrict__ P, const float* __restrict__ as_,
                              const float* __restrict__ ad_,
                              int* __restrict__ cur, int* __restrict__ esrc,
                              float* __restrict__ wv) {
    int e = blockIdx.x * blockDim.x + threadIdx.x;
    if (e >= E) return;
    int s = src[e], d = dst[e];
    float al[4];
    #pragma unroll
    for (int h = 0; h < 4; ++h) al[h] = as_[s * 4 + h] + ad_[d * 4 + h];
    for (int k = 0; k < KE; ++k) {
        float v = ea[e * KE + k];
        #pragma unroll
        for (int h = 0; h < 4; ++h) al[h] += v * P[k * 4 + h];
    }
    int slot = atomicAdd(&cur[d], 1);
    esrc[slot] = s;
    float4 w4 = make_float4(expf(lrelu(al[0])), expf(lrelu(al[1])),
                            expf(lrelu(al[2])), expf(lrelu(al[3])));
    *reinterpret_cast<float4*>(&wv[(size_t)slot * 4]) = w4;
}

// conv3 variant: also stores the edge-attr logit part ae (needed for self-loop mean)
__global__ void k_edge_bucket_c3(const int* __restrict__ src, const int* __restrict__ dst,
                                 const float* __restrict__ ea, const float* __restrict__ P,
                                 const float* __restrict__ as_, const float* __restrict__ ad_,
                                 int* __restrict__ cur, int* __restrict__ esrc,
                                 float* __restrict__ wv) {
    int e = blockIdx.x * blockDim.x + threadIdx.x;
    if (e >= ETT) return;
    int s = src[e], d = dst[e];
    float ae[4] = {0.f, 0.f, 0.f, 0.f};
    #pragma unroll
    for (int k = 0; k < 4; ++k) {
        float v = ea[e * 4 + k];
        #pragma unroll
        for (int h = 0; h < 4; ++h) ae[h] += v * P[k * 4 + h];
    }
    int slot = atomicAdd(&cur[d], 1);
    esrc[slot] = s;
    float4 x4 = make_float4(expf(lrelu(as_[s * 4 + 0] + ad_[d * 4 + 0] + ae[0])),
                            expf(lrelu(as_[s * 4 + 1] + ad_[d * 4 + 1] + ae[1])),
                            expf(lrelu(as_[s * 4 + 2] + ad_[d * 4 + 2] + ae[2])),
                            expf(lrelu(as_[s * 4 + 3] + ad_[d * 4 + 3] + ae[3])));
    *reinterpret_cast<float4*>(&wv[(size_t)slot * 8]) = x4;
    *reinterpret_cast<float4*>(&wv[(size_t)slot * 8 + 4]) = make_float4(ae[0], ae[1], ae[2], ae[3]);
}

// CSR gather conv1/conv2: 32 lanes per dst, float4 per lane, edge loop unrolled x4 (MLP).
// Common-denominator softmax; +bias and relu fused; writes tasks[:, cbase:cbase+128] once.
__global__ __launch_bounds__(256) void k_gather12(const int* __restrict__ rp,
                                                  const int* __restrict__ esrc,
                                                  const float* __restrict__ wv,
                                                  const float* __restrict__ hs,
                                                  const float* __restrict__ bias,
                                                  float* __restrict__ tasks, int cbase) {
    int tid = threadIdx.x;
    int d = blockIdx.x * 8 + (tid >> 5);
    int lane = tid & 31;          // channels 4*lane .. 4*lane+3 (all in head lane>>3)
    int h = lane >> 3;
    int i0 = rp[d], i1 = rp[d + 1];
    float ax = 0.f, ay = 0.f, az = 0.f, aw = 0.f, den = 0.f;
    int i = i0;
    for (; i + 4 <= i1; i += 4) {
        int s0 = esrc[i], s1 = esrc[i + 1], s2 = esrc[i + 2], s3 = esrc[i + 3];
        float w0 = wv[(size_t)i * 4 + h];
        float w1 = wv[(size_t)(i + 1) * 4 + h];
        float w2 = wv[(size_t)(i + 2) * 4 + h];
        float w3 = wv[(size_t)(i + 3) * 4 + h];
        float4 v0 = *reinterpret_cast<const float4*>(&hs[(size_t)s0 * 128 + lane * 4]);
        float4 v1 = *reinterpret_cast<const float4*>(&hs[(size_t)s1 * 128 + lane * 4]);
        float4 v2 = *reinterpret_cast<const float4*>(&hs[(size_t)s2 * 128 + lane * 4]);
        float4 v3 = *reinterpret_cast<const float4*>(&hs[(size_t)s3 * 128 + lane * 4]);
        ax += v0.x * w0 + v1.x * w1 + v2.x * w2 + v3.x * w3;
        ay += v0.y * w0 + v1.y * w1 + v2.y * w2 + v3.y * w3;
        az += v0.z * w0 + v1.z * w1 + v2.z * w2 + v3.z * w3;
        aw += v0.w * w0 + v1.w * w1 + v2.w * w2 + v3.w * w3;
        den += w0 + w1 + w2 + w3;
    }
    for (; i < i1; ++i) {
        int s = esrc[i];
        float w = wv[(size_t)i * 4 + h];
        float4 v = *reinterpret_cast<const float4*>(&hs[(size_t)s * 128 + lane * 4]);
        ax += v.x * w; ay += v.y * w; az += v.z * w; aw += v.w * w;
        den += w;
    }
    float4 b4 = *reinterpret_cast<const float4*>(&bias[lane * 4]);
    float r = 1.f / (den + 1e-16f);
    float4 o = make_float4(fmaxf(ax * r + b4.x, 0.f), fmaxf(ay * r + b4.y, 0.f),
                           fmaxf(az * r + b4.z, 0.f), fmaxf(aw * r + b4.w, 0.f));
    *reinterpret_cast<float4*>(&tasks[(size_t)d * 256 + cbase + lane * 4]) = o;
}

// CSR gather conv3: 32 lanes/dst, per-head denominators, edge loop unrolled x2,
// self-loop (mean edge-attr) message, head-mean, +b3, relu fused. Writes d_out once.
__global__ __launch_bounds__(256) void k_gather_c3(const int* __restrict__ rp,
                                                   const int* __restrict__ esrc,
                                                   const float* __restrict__ wv,
                                                   const float* __restrict__ hs,
                                                   const float* __restrict__ as3,
                                                   const float* __restrict__ ad3,
                                                   const float* __restrict__ b3,
                                                   float* __restrict__ out) {
    int tid = threadIdx.x;
    int d = blockIdx.x * 8 + (tid >> 5);
    int c = tid & 31;
    int i0 = rp[d], i1 = rp[d + 1];
    float acc[4] = {0.f, 0.f, 0.f, 0.f};
    float den[4] = {0.f, 0.f, 0.f, 0.f};
    float aes[4] = {0.f, 0.f, 0.f, 0.f};
    int i = i0;
    for (; i + 2 <= i1; i += 2) {
        int s0 = esrc[i], s1 = esrc[i + 1];
        float4 x0 = *reinterpret_cast<const float4*>(&wv[(size_t)i * 8]);
        float4 a0 = *reinterpret_cast<const float4*>(&wv[(size_t)i * 8 + 4]);
        float4 x1 = *reinterpret_cast<const float4*>(&wv[(size_t)(i + 1) * 8]);
        float4 a1 = *reinterpret_cast<const float4*>(&wv[(size_t)(i + 1) * 8 + 4]);
        const float* h0 = hs + (size_t)s0 * 128 + c;
        const float* h1 = hs + (size_t)s1 * 128 + c;
        acc[0] += x0.x * h0[0]  + x1.x * h1[0];
        acc[1] += x0.y * h0[32] + x1.y * h1[32];
        acc[2] += x0.z * h0[64] + x1.z * h1[64];
        acc[3] += x0.w * h0[96] + x1.w * h1[96];
        den[0] += x0.x + x1.x; den[1] += x0.y + x1.y;
        den[2] += x0.z + x1.z; den[3] += x0.w + x1.w;
        aes[0] += a0.x + a1.x; aes[1] += a0.y + a1.y;
        aes[2] += a0.z + a1.z; aes[3] += a0.w + a1.w;
    }
    for (; i < i1; ++i) {
        int s = esrc[i];
        float4 x4 = *reinterpret_cast<const float4*>(&wv[(size_t)i * 8]);
        float4 a4 = *reinterpret_cast<const float4*>(&wv[(size_t)i * 8 + 4]);
        const float* hrow = hs + (size_t)s * 128 + c;
        acc[0] += x4.x * hrow[0];  acc[1] += x4.y * hrow[32];
        acc[2] += x4.z * hrow[64]; acc[3] += x4.w * hrow[96];
        den[0] += x4.x; den[1] += x4.y; den[2] += x4.z; den[3] += x4.w;
        aes[0] += a4.x; aes[1] += a4.y; aes[2] += a4.z; aes[3] += a4.w;
    }
    float inv = 1.f / fmaxf((float)(i1 - i0), 1.f);
    const float* hd = hs + (size_t)d * 128 + c;
    float o = 0.f;
    #pragma unroll
    for (int h = 0; h < 4; ++h) {
        float m = aes[h] * inv;
        float exl = expf(lrelu(as3[d * 4 + h] + ad3[d * 4 + h] + m));
        float a = acc[h] + exl * hd[h * 32];
        o += a / (den[h] + exl + 1e-16f);
    }
    o = 0.25f * o + b3[c];
    out[(size_t)d * 32 + c] = o > 0.f ? o : 0.f;
}

// hs3 = tasks[50000,256] @ W3[256,128]; fp32, LDS-tiled, 4x4 register blocking
__global__ __launch_bounds__(128) void k_gemm(const float* __restrict__ T,
                                              const float* __restrict__ W,
                                              float* __restrict__ out) {
    __shared__ float sW[64][128];
    __shared__ float sTt[64][16];   // transposed: sTt[k][r]
    int tid = threadIdx.x;
    int tc = tid & 31, tr = tid >> 5;
    int r0 = blockIdx.x * 16;
    float acc[4][4] = {};
    for (int kt = 0; kt < 256; kt += 64) {
        const float4* Wg = reinterpret_cast<const float4*>(W + (size_t)kt * 128);
        float4* sW4 = reinterpret_cast<float4*>(&sW[0][0]);
        #pragma unroll
        for (int i = 0; i < 16; ++i) sW4[i * 128 + tid] = Wg[i * 128 + tid];
        #pragma unroll
        for (int i = 0; i < 2; ++i) {
            int s = i * 128 + tid;
            int r = s >> 4, k4 = s & 15;
            float4 v = *reinterpret_cast<const float4*>(&T[(size_t)(r0 + r) * 256 + kt + k4 * 4]);
            sTt[k4 * 4 + 0][r] = v.x; sTt[k4 * 4 + 1][r] = v.y;
            sTt[k4 * 4 + 2][r] = v.z; sTt[k4 * 4 + 3][r] = v.w;
        }
        __syncthreads();
        #pragma unroll 4
        for (int k = 0; k < 64; ++k) {
            float4 b4 = *reinterpret_cast<const float4*>(&sW[k][tc * 4]);
            float4 a4 = *reinterpret_cast<const float4*>(&sTt[k][tr * 4]);
            float av[4] = {a4.x, a4.y, a4.z, a4.w};
            float bv[4] = {b4.x, b4.y, b4.z, b4.w};
            #pragma unroll
            for (int r = 0; r < 4; ++r)
                #pragma unroll
                for (int c = 0; c < 4; ++c) acc[r][c] += av[r] * bv[c];
        }
        __syncthreads();
    }
    #pragma unroll
    for (int r = 0; r < 4; ++r) {
        float4 o = make_float4(acc[r][0], acc[r][1], acc[r][2], acc[r][3]);
        *reinterpret_cast<float4*>(&out[(size_t)(r0 + tr * 4 + r) * 128 + tc * 4]) = o;
    }
}

extern "C" void kernel_launch(void* const* d_in, const int* in_sizes, int n_in,
                              void* d_out, int out_size, void* d_ws, size_t ws_size,
                              hipStream_t stream) {
    const float* x_data  = (const float*)d_in[0];
    const float* x_tasks = (const float*)d_in[1];
    const float* x_dev   = (const float*)d_in[2];
    const int*   ei_dt   = (const int*)d_in[3];
    const float* ea_dt   = (const float*)d_in[4];
    const int*   ei_vt   = (const int*)d_in[5];
    const float* ea_vt   = (const float*)d_in[6];
    const int*   ei_tt   = (const int*)d_in[7];
    const float* ea_tt   = (const float*)d_in[8];
    const float* Ws1 = (const float*)d_in[9];  const float* Wd1 = (const float*)d_in[10];
    const float* We1 = (const float*)d_in[11]; const float* As1 = (const float*)d_in[12];
    const float* Ad1 = (const float*)d_in[13]; const float* Ae1 = (const float*)d_in[14];
    const float* b1  = (const float*)d_in[15];
    const float* Ws2 = (const float*)d_in[16]; const float* Wd2 = (const float*)d_in[17];
    const float* We2 = (const float*)d_in[18]; const float* As2 = (const float*)d_in[19];
    const float* Ad2 = (const float*)d_in[20]; const float* Ae2 = (const float*)d_in[21];
    const float* b2  = (const float*)d_in[22];
    const float* W3  = (const float*)d_in[23]; const float* We3 = (const float*)d_in[24];
    const float* As3 = (const float*)d_in[25]; const float* Ad3 = (const float*)d_in[26];
    const float* Ae3 = (const float*)d_in[27]; const float* b3  = (const float*)d_in[28];

    if (ws_size < WS_TOTAL * sizeof(float)) return;

    float* w = (float*)d_ws;
    float* tasks = w + OFF_TASKS;
    float* hs    = w + OFF_HS;                 // hs1 (conv1) then hs3 (conv3)
    int*   esrc1 = (int*)(w + OFF_ESRC1);
    int*   esrc2 = (int*)(w + OFF_ESRC2);
    float* wv1   = w + OFF_WV1;
    float* wv3   = w + OFF_WV1;                // aliases wv1 (dead by conv3)
    float* wv2   = w + OFF_WV2;
    int*   esrc3 = (int*)(w + OFF_WV2);        // aliases wv2 (dead by conv3)
    int*   deg   = (int*)(w + OFF_DEG);        // also bucket cursor after scan
    int*   rp    = (int*)(w + OFF_RP);
    float* as1 = w + OFF_AS1;
    float* ad1 = w + OFF_AD1; float* as3 = w + OFF_AD1;   // as3 aliases ad1
    float* ad2 = w + OFF_AD2; float* ad3 = w + OFF_AD2;   // ad3 aliases ad2
    float* hs2 = w + OFF_HS2; float* as2 = w + OFF_AS2;
    float* Qs1 = w + OFF_QS1; float* Qd1 = w + OFF_QD1; float* P1 = w + OFF_P1;
    float* Qs2 = w + OFF_QS2; float* Qd2 = w + OFF_QD2; float* P2 = w + OFF_P2;
    float* P3  = w + OFF_P3;
    float* out = (float*)d_out;

    dim3 B(256);
    #define GRID(n) dim3((unsigned)(((n) + 255) / 256))

    // CSR prep: zero degrees, histogram, per-graph scan (writes rp + cursor copy)
    hipMemsetAsync(deg, 0, 3 * NT * sizeof(int), stream);
    k_proj_small<<<1, 320, 0, stream>>>(Ws1, As1, Wd1, Ad1, We1, Ae1,
                                        Ws2, As2, Wd2, Ad2, We2, Ae2, We3, Ae3,
                                        Qs1, Qd1, P1, Qs2, Qd2, P2, P3);
    k_hist<<<GRID(EDT + EVT + ETT), B, 0, stream>>>(ei_dt, ei_vt, ei_tt, deg);
    k_scan<<<3, 1024, 0, stream>>>(deg, rp);

    // conv1 + conv2 inputs
    k_linproj<<<GRID(NDAT * 128), B, 0, stream>>>(x_data, Ws1, hs, NDAT, 8);
    k_alpha<<<GRID(NDAT * 4), B, 0, stream>>>(x_data, Qs1, as1, NDAT, 8);
    k_alpha2<<<GRID(NT * 4), B, 0, stream>>>(x_tasks, Qd1, Qd2, ad1, ad2, NT, 16);
    k_edge_bucket<<<GRID(EDT), B, 0, stream>>>(ei_dt, ei_dt + EDT, ea_dt, EDT, 8,
                                               P1, as1, ad1, deg, esrc1, wv1);
    k_linproj<<<GRID(NDEV * 128), B, 0, stream>>>(x_dev, Ws2, hs2, NDEV, 8);
    k_alpha<<<GRID(NDEV * 4), B, 0, stream>>>(x_dev, Qs2, as2, NDEV, 8);
    k_edge_bucket<<<GRID(EVT), B, 0, stream>>>(ei_vt, ei_vt + EVT, ea_vt, EVT, 6,
                                               P2, as2, ad2, deg + NT, esrc2, wv2);
    // gathers (write tasks fully, bias+relu fused)
    k_gather12<<<dim3(NT / 8), B, 0, stream>>>(rp, esrc1, wv1, hs, b1, tasks, 0);
    k_gather12<<<dim3(NT / 8), B, 0, stream>>>(rp + (NT + 1), esrc2, wv2, hs2, b2, tasks, 128);

    // conv3: tasks -> tasks
    k_gemm<<<dim3(NT / 16), dim3(128), 0, stream>>>(tasks, W3, hs);
    k_alpha_from_h2<<<GRID(NT * 4), B, 0, stream>>>(hs, As3, Ad3, as3, ad3, NT);
    k_edge_bucket_c3<<<GRID(ETT), B, 0, stream>>>(ei_tt, ei_tt + ETT, ea_tt, P3,
                                                  as3, ad3, deg + 2 * NT, esrc3, wv3);
    k_gather_c3<<<dim3(NT / 8), B, 0, stream>>>(rp + 2 * (NT + 1), esrc3, wv3, hs,
                                                as3, ad3, b3, out);
    #undef GRID
}

// Round 4
// 379.655 us; speedup vs baseline: 2.7108x; 1.1898x over previous
//
#include <hip/hip_runtime.h>
#include <math.h>

static const int NT = 50000, NDAT = 20000, NDEV = 4;
static const int EDT = 800000, EVT = 200000, ETT = 400000;

// scan geometry: 3 graphs x 25 tiles of 2048 (256 thr x 8 elems)
static const int SCAN_TILE = 2048, SCAN_NB = 25;

// ---------------- workspace layout (float offsets), liveness-aliased ----------------
static const size_t OFF_TASKS = 0;                   // 12,800,000  [NT,256] fp32
static const size_t OFF_HS    = 12800000;            //  6,400,000  hs1 (2.56M) then hs3 (6.4M)
static const size_t OFF_ESRC1 = OFF_HS + 2560000;    //    800,000  ints (dead before gemm writes hs3)
static const size_t OFF_ESRC2 = OFF_HS + 3360000;    //    200,000  ints (dead before gemm)
static const size_t OFF_WV1   = 19200000;            //  3,200,000  conv1 ex4/slot; wv3 (8/slot) reuses
static const size_t OFF_WV2   = 22400000;            //    800,000  conv2 ex4/slot; esrc3 reuses
static const size_t OFF_DEG   = 23200000;            //    150,000  3 x NT ints; becomes bucket cursor
static const size_t OFF_RP    = 23350000;            //    150,003  3 x (NT+1) ints
static const size_t OFF_AS1   = 23500004;            //     80,000
static const size_t OFF_AD1   = 23580004;            //    200,000  as3 reuses
static const size_t OFF_AD2   = 23780004;            //    200,000  ad3 reuses
static const size_t OFF_HS2   = 23980004;            //        512
static const size_t OFF_AS2   = 23980516;            //         16
static const size_t OFF_QS1   = 23980532;            //         32
static const size_t OFF_QD1   = 23980564;            //         64
static const size_t OFF_P1    = 23980628;            //         32
static const size_t OFF_QS2   = 23980660;            //         32
static const size_t OFF_QD2   = 23980692;            //         64
static const size_t OFF_P2    = 23980756;            //         24
static const size_t OFF_P3    = 23980780;            //         16
static const size_t OFF_BSUM  = 23980796;            //        128 ints (75 used)
static const size_t WS_TOTAL  = 23980924;            // floats (~96 MiB)

__device__ __forceinline__ float lrelu(float a) { return a > 0.f ? a : 0.2f * a; }

// Q[k][h] = sum_c W[k*128 + h*32 + c] * A[h*32 + c], for all 7 small matrices
__global__ void k_proj_small(const float* Ws1, const float* As1,
                             const float* Wd1, const float* Ad1,
                             const float* We1, const float* Ae1,
                             const float* Ws2, const float* As2,
                             const float* Wd2, const float* Ad2,
                             const float* We2, const float* Ae2,
                             const float* We3, const float* Ae3,
                             float* Qs1, float* Qd1, float* P1,
                             float* Qs2, float* Qd2, float* P2, float* P3) {
    int t = threadIdx.x;
    const float *W, *A; float* O; int u;
    if      (t < 32)  { W = Ws1; A = As1; O = Qs1; u = t; }
    else if (t < 96)  { W = Wd1; A = Ad1; O = Qd1; u = t - 32; }
    else if (t < 128) { W = We1; A = Ae1; O = P1;  u = t - 96; }
    else if (t < 160) { W = Ws2; A = As2; O = Qs2; u = t - 128; }
    else if (t < 224) { W = Wd2; A = Ad2; O = Qd2; u = t - 160; }
    else if (t < 248) { W = We2; A = Ae2; O = P2;  u = t - 224; }
    else if (t < 264) { W = We3; A = Ae3; O = P3;  u = t - 248; }
    else return;
    int k = u >> 2, h = u & 3;
    float acc = 0.f;
    for (int c = 0; c < 32; ++c) acc += W[k * 128 + h * 32 + c] * A[h * 32 + c];
    O[k * 4 + h] = acc;
}

// out[n][j] = sum_k x[n*K+k] * W[k*128+j]
__global__ void k_linproj(const float* __restrict__ x, const float* __restrict__ W,
                          float* __restrict__ out, int N, int K) {
    int idx = blockIdx.x * blockDim.x + threadIdx.x;
    if (idx >= N * 128) return;
    int n = idx >> 7, j = idx & 127;
    float acc = 0.f;
    for (int k = 0; k < K; ++k) acc += x[n * K + k] * W[k * 128 + j];
    out[idx] = acc;
}

// out[n][h] = sum_k x[n*K+k] * Q[k*4+h]
__global__ void k_alpha(const float* __restrict__ x, const float* __restrict__ Q,
                        float* __restrict__ out, int N, int K) {
    int idx = blockIdx.x * blockDim.x + threadIdx.x;
    if (idx >= N * 4) return;
    int n = idx >> 2, h = idx & 3;
    float acc = 0.f;
    for (int k = 0; k < K; ++k) acc += x[n * K + k] * Q[k * 4 + h];
    out[idx] = acc;
}

// fused: adA[n][h] = x@Qa, adB[n][h] = x@Qb  (one pass over x_tasks)
__global__ void k_alpha2(const float* __restrict__ x, const float* __restrict__ Qa,
                         const float* __restrict__ Qb, float* __restrict__ oa,
                         float* __restrict__ ob, int N, int K) {
    int idx = blockIdx.x * blockDim.x + threadIdx.x;
    if (idx >= N * 4) return;
    int n = idx >> 2, h = idx & 3;
    float a = 0.f, b = 0.f;
    for (int k = 0; k < K; ++k) {
        float v = x[n * K + k];
        a += v * Qa[k * 4 + h];
        b += v * Qb[k * 4 + h];
    }
    oa[idx] = a; ob[idx] = b;
}

// fused: as3[n][h] and ad3[n][h] from one pass over hs row
__global__ void k_alpha_from_h2(const float* __restrict__ hs, const float* __restrict__ As,
                                const float* __restrict__ Ad, float* __restrict__ oa,
                                float* __restrict__ ob, int N) {
    int idx = blockIdx.x * blockDim.x + threadIdx.x;
    if (idx >= N * 4) return;
    int n = idx >> 2, h = idx & 3;
    float a = 0.f, b = 0.f;
    #pragma unroll
    for (int c = 0; c < 32; ++c) {
        float v = hs[n * 128 + h * 32 + c];
        a += v * As[h * 32 + c];
        b += v * Ad[h * 32 + c];
    }
    oa[idx] = a; ob[idx] = b;
}

// degree histogram for all 3 graphs in one grid
__global__ void k_hist(const int* __restrict__ dt, const int* __restrict__ vt,
                       const int* __restrict__ tt, int* __restrict__ deg) {
    int e = blockIdx.x * blockDim.x + threadIdx.x;
    if (e < EDT) atomicAdd(&deg[dt[EDT + e]], 1);
    else if (e < EDT + EVT) atomicAdd(&deg[NT + vt[EVT + (e - EDT)]], 1);
    else if (e < EDT + EVT + ETT) atomicAdd(&deg[2 * NT + tt[ETT + (e - EDT - EVT)]], 1);
}

// scan phase A: per-tile block reduce -> bsum[75]; coalesced int4 loads
__global__ __launch_bounds__(256) void k_scan_part(const int* __restrict__ deg,
                                                   int* __restrict__ bsum) {
    int b = blockIdx.x;
    int g = b / SCAN_NB, t = b % SCAN_NB;
    int base = t * SCAN_TILE + threadIdx.x * 8;     // within graph
    const int* dg = deg + (size_t)g * NT;
    int s = 0;
    if (base + 8 <= NT) {
        int4 a = *reinterpret_cast<const int4*>(dg + base);
        int4 c = *reinterpret_cast<const int4*>(dg + base + 4);
        s = a.x + a.y + a.z + a.w + c.x + c.y + c.z + c.w;
    } else {
        for (int i = 0; i < 8; ++i) if (base + i < NT) s += dg[base + i];
    }
    __shared__ int red[256];
    red[threadIdx.x] = s;
    __syncthreads();
    for (int off = 128; off > 0; off >>= 1) {
        if (threadIdx.x < off) red[threadIdx.x] += red[threadIdx.x + off];
        __syncthreads();
    }
    if (threadIdx.x == 0) bsum[b] = red[0];
}

// scan phase B: one wave; exclusive-scan the 25 tile sums of each graph; write graph totals
__global__ void k_scan_bsum(int* __restrict__ bsum, int* __restrict__ rp) {
    int lane = threadIdx.x;            // 64 lanes
    for (int g = 0; g < 3; ++g) {
        int v = (lane < SCAN_NB) ? bsum[g * SCAN_NB + lane] : 0;
        int inc = v;
        #pragma unroll
        for (int off = 1; off < 32; off <<= 1) {
            int o = __shfl_up(inc, off, 32);
            if ((lane & 31) >= off) inc += o;
        }
        if (lane < SCAN_NB) bsum[g * SCAN_NB + lane] = inc - v;
        if (lane == SCAN_NB - 1) rp[(size_t)g * (NT + 1) + NT] = inc;
    }
}

// scan phase C: per-tile exclusive scan + tile offset; writes rp and deg (bucket cursor)
__global__ __launch_bounds__(256) void k_scan_final(int* __restrict__ deg,
                                                    const int* __restrict__ bsum,
                                                    int* __restrict__ rp) {
    int b = blockIdx.x;
    int g = b / SCAN_NB, t = b % SCAN_NB;
    int tid = threadIdx.x;
    int base = t * SCAN_TILE + tid * 8;
    int* dg = deg + (size_t)g * NT;
    int* rpg = rp + (size_t)g * (NT + 1);
    int v[8];
    int s = 0;
    if (base + 8 <= NT) {
        int4 a = *reinterpret_cast<const int4*>(dg + base);
        int4 c = *reinterpret_cast<const int4*>(dg + base + 4);
        v[0] = a.x; v[1] = a.y; v[2] = a.z; v[3] = a.w;
        v[4] = c.x; v[5] = c.y; v[6] = c.z; v[7] = c.w;
        s = v[0] + v[1] + v[2] + v[3] + v[4] + v[5] + v[6] + v[7];
    } else {
        #pragma unroll
        for (int i = 0; i < 8; ++i) {
            v[i] = (base + i < NT) ? dg[base + i] : 0;
            s += v[i];
        }
    }
    __shared__ int sums[256];
    sums[tid] = s;
    __syncthreads();
    for (int off = 1; off < 256; off <<= 1) {
        int x = (tid >= off) ? sums[tid - off] : 0;
        __syncthreads();
        sums[tid] += x;
        __syncthreads();
    }
    int run = bsum[b] + (tid ? sums[tid - 1] : 0);
    #pragma unroll
    for (int i = 0; i < 8; ++i) {
        int idx = base + i;
        if (idx < NT) { rpg[idx] = run; dg[idx] = run; run += v[i]; }
    }
}

// fused: per-edge attention exp + bucket into CSR slots (conv1/conv2)
__global__ void k_edge_bucket(const int* __restrict__ src, const int* __restrict__ dst,
                              const float* __restrict__ ea, int E, int KE,
                              const float* __restrict__ P, const float* __restrict__ as_,
                              const float* __restrict__ ad_,
                              int* __restrict__ cur, int* __restrict__ esrc,
                              float* __restrict__ wv) {
    int e = blockIdx.x * blockDim.x + threadIdx.x;
    if (e >= E) return;
    int s = src[e], d = dst[e];
    float al[4];
    #pragma unroll
    for (int h = 0; h < 4; ++h) al[h] = as_[s * 4 + h] + ad_[d * 4 + h];
    for (int k = 0; k < KE; ++k) {
        float v = ea[e * KE + k];
        #pragma unroll
        for (int h = 0; h < 4; ++h) al[h] += v * P[k * 4 + h];
    }
    int slot = atomicAdd(&cur[d], 1);
    esrc[slot] = s;
    float4 w4 = make_float4(expf(lrelu(al[0])), expf(lrelu(al[1])),
                            expf(lrelu(al[2])), expf(lrelu(al[3])));
    *reinterpret_cast<float4*>(&wv[(size_t)slot * 4]) = w4;
}

// conv3 variant: also stores the edge-attr logit part ae (needed for self-loop mean)
__global__ void k_edge_bucket_c3(const int* __restrict__ src, const int* __restrict__ dst,
                                 const float* __restrict__ ea, const float* __restrict__ P,
                                 const float* __restrict__ as_, const float* __restrict__ ad_,
                                 int* __restrict__ cur, int* __restrict__ esrc,
                                 float* __restrict__ wv) {
    int e = blockIdx.x * blockDim.x + threadIdx.x;
    if (e >= ETT) return;
    int s = src[e], d = dst[e];
    float ae[4] = {0.f, 0.f, 0.f, 0.f};
    #pragma unroll
    for (int k = 0; k < 4; ++k) {
        float v = ea[e * 4 + k];
        #pragma unroll
        for (int h = 0; h < 4; ++h) ae[h] += v * P[k * 4 + h];
    }
    int slot = atomicAdd(&cur[d], 1);
    esrc[slot] = s;
    float4 x4 = make_float4(expf(lrelu(as_[s * 4 + 0] + ad_[d * 4 + 0] + ae[0])),
                            expf(lrelu(as_[s * 4 + 1] + ad_[d * 4 + 1] + ae[1])),
                            expf(lrelu(as_[s * 4 + 2] + ad_[d * 4 + 2] + ae[2])),
                            expf(lrelu(as_[s * 4 + 3] + ad_[d * 4 + 3] + ae[3])));
    *reinterpret_cast<float4*>(&wv[(size_t)slot * 8]) = x4;
    *reinterpret_cast<float4*>(&wv[(size_t)slot * 8 + 4]) = make_float4(ae[0], ae[1], ae[2], ae[3]);
}

// CSR gather conv1/conv2: 32 lanes per dst, float4 per lane, edge loop unrolled x4 (MLP).
__global__ __launch_bounds__(256) void k_gather12(const int* __restrict__ rp,
                                                  const int* __restrict__ esrc,
                                                  const float* __restrict__ wv,
                                                  const float* __restrict__ hs,
                                                  const float* __restrict__ bias,
                                                  float* __restrict__ tasks, int cbase) {
    int tid = threadIdx.x;
    int d = blockIdx.x * 8 + (tid >> 5);
    int lane = tid & 31;
    int h = lane >> 3;
    int i0 = rp[d], i1 = rp[d + 1];
    float ax = 0.f, ay = 0.f, az = 0.f, aw = 0.f, den = 0.f;
    int i = i0;
    for (; i + 4 <= i1; i += 4) {
        int s0 = esrc[i], s1 = esrc[i + 1], s2 = esrc[i + 2], s3 = esrc[i + 3];
        float w0 = wv[(size_t)i * 4 + h];
        float w1 = wv[(size_t)(i + 1) * 4 + h];
        float w2 = wv[(size_t)(i + 2) * 4 + h];
        float w3 = wv[(size_t)(i + 3) * 4 + h];
        float4 v0 = *reinterpret_cast<const float4*>(&hs[(size_t)s0 * 128 + lane * 4]);
        float4 v1 = *reinterpret_cast<const float4*>(&hs[(size_t)s1 * 128 + lane * 4]);
        float4 v2 = *reinterpret_cast<const float4*>(&hs[(size_t)s2 * 128 + lane * 4]);
        float4 v3 = *reinterpret_cast<const float4*>(&hs[(size_t)s3 * 128 + lane * 4]);
        ax += v0.x * w0 + v1.x * w1 + v2.x * w2 + v3.x * w3;
        ay += v0.y * w0 + v1.y * w1 + v2.y * w2 + v3.y * w3;
        az += v0.z * w0 + v1.z * w1 + v2.z * w2 + v3.z * w3;
        aw += v0.w * w0 + v1.w * w1 + v2.w * w2 + v3.w * w3;
        den += w0 + w1 + w2 + w3;
    }
    for (; i < i1; ++i) {
        int s = esrc[i];
        float w = wv[(size_t)i * 4 + h];
        float4 v = *reinterpret_cast<const float4*>(&hs[(size_t)s * 128 + lane * 4]);
        ax += v.x * w; ay += v.y * w; az += v.z * w; aw += v.w * w;
        den += w;
    }
    float4 b4 = *reinterpret_cast<const float4*>(&bias[lane * 4]);
    float r = 1.f / (den + 1e-16f);
    float4 o = make_float4(fmaxf(ax * r + b4.x, 0.f), fmaxf(ay * r + b4.y, 0.f),
                           fmaxf(az * r + b4.z, 0.f), fmaxf(aw * r + b4.w, 0.f));
    *reinterpret_cast<float4*>(&tasks[(size_t)d * 256 + cbase + lane * 4]) = o;
}

// CSR gather conv3: 32 lanes/dst, per-head denominators, edge loop unrolled x2,
// self-loop (mean edge-attr) message, head-mean, +b3, relu fused. Writes d_out once.
__global__ __launch_bounds__(256) void k_gather_c3(const int* __restrict__ rp,
                                                   const int* __restrict__ esrc,
                                                   const float* __restrict__ wv,
                                                   const float* __restrict__ hs,
                                                   const float* __restrict__ as3,
                                                   const float* __restrict__ ad3,
                                                   const float* __restrict__ b3,
                                                   float* __restrict__ out) {
    int tid = threadIdx.x;
    int d = blockIdx.x * 8 + (tid >> 5);
    int c = tid & 31;
    int i0 = rp[d], i1 = rp[d + 1];
    float acc[4] = {0.f, 0.f, 0.f, 0.f};
    float den[4] = {0.f, 0.f, 0.f, 0.f};
    float aes[4] = {0.f, 0.f, 0.f, 0.f};
    int i = i0;
    for (; i + 2 <= i1; i += 2) {
        int s0 = esrc[i], s1 = esrc[i + 1];
        float4 x0 = *reinterpret_cast<const float4*>(&wv[(size_t)i * 8]);
        float4 a0 = *reinterpret_cast<const float4*>(&wv[(size_t)i * 8 + 4]);
        float4 x1 = *reinterpret_cast<const float4*>(&wv[(size_t)(i + 1) * 8]);
        float4 a1 = *reinterpret_cast<const float4*>(&wv[(size_t)(i + 1) * 8 + 4]);
        const float* h0 = hs + (size_t)s0 * 128 + c;
        const float* h1 = hs + (size_t)s1 * 128 + c;
        acc[0] += x0.x * h0[0]  + x1.x * h1[0];
        acc[1] += x0.y * h0[32] + x1.y * h1[32];
        acc[2] += x0.z * h0[64] + x1.z * h1[64];
        acc[3] += x0.w * h0[96] + x1.w * h1[96];
        den[0] += x0.x + x1.x; den[1] += x0.y + x1.y;
        den[2] += x0.z + x1.z; den[3] += x0.w + x1.w;
        aes[0] += a0.x + a1.x; aes[1] += a0.y + a1.y;
        aes[2] += a0.z + a1.z; aes[3] += a0.w + a1.w;
    }
    for (; i < i1; ++i) {
        int s = esrc[i];
        float4 x4 = *reinterpret_cast<const float4*>(&wv[(size_t)i * 8]);
        float4 a4 = *reinterpret_cast<const float4*>(&wv[(size_t)i * 8 + 4]);
        const float* hrow = hs + (size_t)s * 128 + c;
        acc[0] += x4.x * hrow[0];  acc[1] += x4.y * hrow[32];
        acc[2] += x4.z * hrow[64]; acc[3] += x4.w * hrow[96];
        den[0] += x4.x; den[1] += x4.y; den[2] += x4.z; den[3] += x4.w;
        aes[0] += a4.x; aes[1] += a4.y; aes[2] += a4.z; aes[3] += a4.w;
    }
    float inv = 1.f / fmaxf((float)(i1 - i0), 1.f);
    const float* hd = hs + (size_t)d * 128 + c;
    float o = 0.f;
    #pragma unroll
    for (int h = 0; h < 4; ++h) {
        float m = aes[h] * inv;
        float exl = expf(lrelu(as3[d * 4 + h] + ad3[d * 4 + h] + m));
        float a = acc[h] + exl * hd[h * 32];
        o += a / (den[h] + exl + 1e-16f);
    }
    o = 0.25f * o + b3[c];
    out[(size_t)d * 32 + c] = o > 0.f ? o : 0.f;
}

// hs3 = tasks[50000,256] @ W3[256,128]; fp32, LDS-tiled, 4x4 register blocking
__global__ __launch_bounds__(128) void k_gemm(const float* __restrict__ T,
                                              const float* __restrict__ W,
                                              float* __restrict__ out) {
    __shared__ float sW[64][128];
    __shared__ float sTt[64][16];   // transposed: sTt[k][r]
    int tid = threadIdx.x;
    int tc = tid & 31, tr = tid >> 5;
    int r0 = blockIdx.x * 16;
    float acc[4][4] = {};
    for (int kt = 0; kt < 256; kt += 64) {
        const float4* Wg = reinterpret_cast<const float4*>(W + (size_t)kt * 128);
        float4* sW4 = reinterpret_cast<float4*>(&sW[0][0]);
        #pragma unroll
        for (int i = 0; i < 16; ++i) sW4[i * 128 + tid] = Wg[i * 128 + tid];
        #pragma unroll
        for (int i = 0; i < 2; ++i) {
            int s = i * 128 + tid;
            int r = s >> 4, k4 = s & 15;
            float4 v = *reinterpret_cast<const float4*>(&T[(size_t)(r0 + r) * 256 + kt + k4 * 4]);
            sTt[k4 * 4 + 0][r] = v.x; sTt[k4 * 4 + 1][r] = v.y;
            sTt[k4 * 4 + 2][r] = v.z; sTt[k4 * 4 + 3][r] = v.w;
        }
        __syncthreads();
        #pragma unroll 4
        for (int k = 0; k < 64; ++k) {
            float4 b4 = *reinterpret_cast<const float4*>(&sW[k][tc * 4]);
            float4 a4 = *reinterpret_cast<const float4*>(&sTt[k][tr * 4]);
            float av[4] = {a4.x, a4.y, a4.z, a4.w};
            float bv[4] = {b4.x, b4.y, b4.z, b4.w};
            #pragma unroll
            for (int r = 0; r < 4; ++r)
                #pragma unroll
                for (int c = 0; c < 4; ++c) acc[r][c] += av[r] * bv[c];
        }
        __syncthreads();
    }
    #pragma unroll
    for (int r = 0; r < 4; ++r) {
        float4 o = make_float4(acc[r][0], acc[r][1], acc[r][2], acc[r][3]);
        *reinterpret_cast<float4*>(&out[(size_t)(r0 + tr * 4 + r) * 128 + tc * 4]) = o;
    }
}

extern "C" void kernel_launch(void* const* d_in, const int* in_sizes, int n_in,
                              void* d_out, int out_size, void* d_ws, size_t ws_size,
                              hipStream_t stream) {
    const float* x_data  = (const float*)d_in[0];
    const float* x_tasks = (const float*)d_in[1];
    const float* x_dev   = (const float*)d_in[2];
    const int*   ei_dt   = (const int*)d_in[3];
    const float* ea_dt   = (const float*)d_in[4];
    const int*   ei_vt   = (const int*)d_in[5];
    const float* ea_vt   = (const float*)d_in[6];
    const int*   ei_tt   = (const int*)d_in[7];
    const float* ea_tt   = (const float*)d_in[8];
    const float* Ws1 = (const float*)d_in[9];  const float* Wd1 = (const float*)d_in[10];
    const float* We1 = (const float*)d_in[11]; const float* As1 = (const float*)d_in[12];
    const float* Ad1 = (const float*)d_in[13]; const float* Ae1 = (const float*)d_in[14];
    const float* b1  = (const float*)d_in[15];
    const float* Ws2 = (const float*)d_in[16]; const float* Wd2 = (const float*)d_in[17];
    const float* We2 = (const float*)d_in[18]; const float* As2 = (const float*)d_in[19];
    const float* Ad2 = (const float*)d_in[20]; const float* Ae2 = (const float*)d_in[21];
    const float* b2  = (const float*)d_in[22];
    const float* W3  = (const float*)d_in[23]; const float* We3 = (const float*)d_in[24];
    const float* As3 = (const float*)d_in[25]; const float* Ad3 = (const float*)d_in[26];
    const float* Ae3 = (const float*)d_in[27]; const float* b3  = (const float*)d_in[28];

    if (ws_size < WS_TOTAL * sizeof(float)) return;

    float* w = (float*)d_ws;
    float* tasks = w + OFF_TASKS;
    float* hs    = w + OFF_HS;                 // hs1 (conv1) then hs3 (conv3)
    int*   esrc1 = (int*)(w + OFF_ESRC1);
    int*   esrc2 = (int*)(w + OFF_ESRC2);
    float* wv1   = w + OFF_WV1;
    float* wv3   = w + OFF_WV1;                // aliases wv1 (dead by conv3)
    float* wv2   = w + OFF_WV2;
    int*   esrc3 = (int*)(w + OFF_WV2);        // aliases wv2 (dead by conv3)
    int*   deg   = (int*)(w + OFF_DEG);        // also bucket cursor after scan
    int*   rp    = (int*)(w + OFF_RP);
    int*   bsum  = (int*)(w + OFF_BSUM);
    float* as1 = w + OFF_AS1;
    float* ad1 = w + OFF_AD1; float* as3 = w + OFF_AD1;   // as3 aliases ad1
    float* ad2 = w + OFF_AD2; float* ad3 = w + OFF_AD2;   // ad3 aliases ad2
    float* hs2 = w + OFF_HS2; float* as2 = w + OFF_AS2;
    float* Qs1 = w + OFF_QS1; float* Qd1 = w + OFF_QD1; float* P1 = w + OFF_P1;
    float* Qs2 = w + OFF_QS2; float* Qd2 = w + OFF_QD2; float* P2 = w + OFF_P2;
    float* P3  = w + OFF_P3;
    float* out = (float*)d_out;

    dim3 B(256);
    #define GRID(n) dim3((unsigned)(((n) + 255) / 256))

    // CSR prep: zero degrees, histogram, hierarchical scan (rp + cursor copy in deg)
    hipMemsetAsync(deg, 0, 3 * NT * sizeof(int), stream);
    k_proj_small<<<1, 320, 0, stream>>>(Ws1, As1, Wd1, Ad1, We1, Ae1,
                                        Ws2, As2, Wd2, Ad2, We2, Ae2, We3, Ae3,
                                        Qs1, Qd1, P1, Qs2, Qd2, P2, P3);
    k_hist<<<GRID(EDT + EVT + ETT), B, 0, stream>>>(ei_dt, ei_vt, ei_tt, deg);
    k_scan_part<<<dim3(3 * SCAN_NB), B, 0, stream>>>(deg, bsum);
    k_scan_bsum<<<1, 64, 0, stream>>>(bsum, rp);
    k_scan_final<<<dim3(3 * SCAN_NB), B, 0, stream>>>(deg, bsum, rp);

    // conv1 + conv2 inputs
    k_linproj<<<GRID(NDAT * 128), B, 0, stream>>>(x_data, Ws1, hs, NDAT, 8);
    k_alpha<<<GRID(NDAT * 4), B, 0, stream>>>(x_data, Qs1, as1, NDAT, 8);
    k_alpha2<<<GRID(NT * 4), B, 0, stream>>>(x_tasks, Qd1, Qd2, ad1, ad2, NT, 16);
    k_edge_bucket<<<GRID(EDT), B, 0, stream>>>(ei_dt, ei_dt + EDT, ea_dt, EDT, 8,
                                               P1, as1, ad1, deg, esrc1, wv1);
    k_linproj<<<GRID(NDEV * 128), B, 0, stream>>>(x_dev, Ws2, hs2, NDEV, 8);
    k_alpha<<<GRID(NDEV * 4), B, 0, stream>>>(x_dev, Qs2, as2, NDEV, 8);
    k_edge_bucket<<<GRID(EVT), B, 0, stream>>>(ei_vt, ei_vt + EVT, ea_vt, EVT, 6,
                                               P2, as2, ad2, deg + NT, esrc2, wv2);
    // gathers (write tasks fully, bias+relu fused)
    k_gather12<<<dim3(NT / 8), B, 0, stream>>>(rp, esrc1, wv1, hs, b1, tasks, 0);
    k_gather12<<<dim3(NT / 8), B, 0, stream>>>(rp + (NT + 1), esrc2, wv2, hs2, b2, tasks, 128);

    // conv3: tasks -> tasks
    k_gemm<<<dim3(NT / 16), dim3(128), 0, stream>>>(tasks, W3, hs);
    k_alpha_from_h2<<<GRID(NT * 4), B, 0, stream>>>(hs, As3, Ad3, as3, ad3, NT);
    k_edge_bucket_c3<<<GRID(ETT), B, 0, stream>>>(ei_tt, ei_tt + ETT, ea_tt, P3,
                                                  as3, ad3, deg + 2 * NT, esrc3, wv3);
    k_gather_c3<<<dim3(NT / 8), B, 0, stream>>>(rp + 2 * (NT + 1), esrc3, wv3, hs,
                                                as3, ad3, b3, out);
    #undef GRID
}

// Round 5
// 331.151 us; speedup vs baseline: 3.1078x; 1.1465x over previous
//
#include <hip/hip_runtime.h>
#include <math.h>

static const int NT = 50000, NDAT = 20000, NDEV = 4;
static const int EDT = 800000, EVT = 200000, ETT = 400000;

// scan geometry: 3 graphs x 25 tiles of 2048 (256 thr x 8 elems)
static const int SCAN_TILE = 2048, SCAN_NB = 25;

// ---------------- workspace layout (float offsets), liveness-aliased ----------------
static const size_t OFF_TASKS = 0;                   // 12,800,000  [NT,256] fp32
static const size_t OFF_HS    = 12800000;            //  6,400,000  hs1 (2.56M) then hs3 (6.4M)
static const size_t OFF_ESRC1 = OFF_HS + 2560000;    //    800,000  ints (dead before gemm writes hs3)
static const size_t OFF_ESRC2 = OFF_HS + 3360000;    //    200,000  ints (dead before gemm)
static const size_t OFF_WV1   = 19200000;            //  3,200,000  conv1 ex4/slot; wv3 (8/slot) reuses
static const size_t OFF_WV2   = 22400000;            //    800,000  conv2 ex4/slot; esrc3 reuses
static const size_t OFF_DEG   = 23200000;            //    150,000  3 x NT ints; becomes bucket cursor
static const size_t OFF_RP    = 23350000;            //    150,003  3 x (NT+1) ints
static const size_t OFF_AS1   = 23500004;            //     80,000
static const size_t OFF_AD1   = 23580004;            //    200,000  as3 reuses
static const size_t OFF_AD2   = 23780004;            //    200,000  ad3 reuses
static const size_t OFF_HS2   = 23980004;            //        512
static const size_t OFF_AS2   = 23980516;            //         16
static const size_t OFF_QS1   = 23980532;            //         32
static const size_t OFF_QD1   = 23980564;            //         64
static const size_t OFF_P1    = 23980628;            //         32
static const size_t OFF_QS2   = 23980660;            //         32
static const size_t OFF_QD2   = 23980692;            //         64
static const size_t OFF_P2    = 23980756;            //         24
static const size_t OFF_P3    = 23980780;            //         16
static const size_t OFF_BSUM  = 23980796;            //        128 ints (75 used)
static const size_t OFF_W3HT  = 23980924;            //     16,384 (32768 ushorts, [128n][256k])
static const size_t OFF_W3LT  = 23997308;            //     16,384
static const size_t WS_TOTAL  = 24013692;            // floats (~96 MiB)

typedef short v8s __attribute__((ext_vector_type(8)));
typedef float v4f __attribute__((ext_vector_type(4)));

__device__ __forceinline__ float lrelu(float a) { return a > 0.f ? a : 0.2f * a; }
__device__ __forceinline__ unsigned short f2bf(float x) {
    unsigned int u = __float_as_uint(x);
    return (unsigned short)((u + 0x7FFFu + ((u >> 16) & 1u)) >> 16);
}
__device__ __forceinline__ float bf2f(unsigned short h) {
    return __uint_as_float(((unsigned int)h) << 16);
}
// split 8 floats into bf16 hi + bf16 lo fragments
__device__ __forceinline__ void cvt_split(const float4& A, const float4& B, v8s& hi, v8s& lo) {
    union { unsigned short u[8]; v8s v; } H, L;
    float f[8] = {A.x, A.y, A.z, A.w, B.x, B.y, B.z, B.w};
    #pragma unroll
    for (int i = 0; i < 8; ++i) {
        unsigned short h = f2bf(f[i]);
        H.u[i] = h;
        L.u[i] = f2bf(f[i] - bf2f(h));
    }
    hi = H.v; lo = L.v;
}

// Q[k][h] = sum_c W[k*128 + h*32 + c] * A[h*32 + c], for all 7 small matrices
__global__ void k_proj_small(const float* Ws1, const float* As1,
                             const float* Wd1, const float* Ad1,
                             const float* We1, const float* Ae1,
                             const float* Ws2, const float* As2,
                             const float* Wd2, const float* Ad2,
                             const float* We2, const float* Ae2,
                             const float* We3, const float* Ae3,
                             float* Qs1, float* Qd1, float* P1,
                             float* Qs2, float* Qd2, float* P2, float* P3) {
    int t = threadIdx.x;
    const float *W, *A; float* O; int u;
    if      (t < 32)  { W = Ws1; A = As1; O = Qs1; u = t; }
    else if (t < 96)  { W = Wd1; A = Ad1; O = Qd1; u = t - 32; }
    else if (t < 128) { W = We1; A = Ae1; O = P1;  u = t - 96; }
    else if (t < 160) { W = Ws2; A = As2; O = Qs2; u = t - 128; }
    else if (t < 224) { W = Wd2; A = Ad2; O = Qd2; u = t - 160; }
    else if (t < 248) { W = We2; A = Ae2; O = P2;  u = t - 224; }
    else if (t < 264) { W = We3; A = Ae3; O = P3;  u = t - 248; }
    else return;
    int k = u >> 2, h = u & 3;
    float acc = 0.f;
    for (int c = 0; c < 32; ++c) acc += W[k * 128 + h * 32 + c] * A[h * 32 + c];
    O[k * 4 + h] = acc;
}

// one-time: split W3[256,128] into bf16 hi/lo, transposed to [128n][256k]
__global__ void k_w3split(const float* __restrict__ W3, unsigned short* __restrict__ hiT,
                          unsigned short* __restrict__ loT) {
    int idx = blockIdx.x * blockDim.x + threadIdx.x;
    if (idx >= 256 * 128) return;
    int k = idx >> 7, n = idx & 127;
    float x = W3[idx];
    unsigned short h = f2bf(x);
    hiT[n * 256 + k] = h;
    loT[n * 256 + k] = f2bf(x - bf2f(h));
}

// out[n][j] = sum_k x[n*K+k] * W[k*128+j]
__global__ void k_linproj(const float* __restrict__ x, const float* __restrict__ W,
                          float* __restrict__ out, int N, int K) {
    int idx = blockIdx.x * blockDim.x + threadIdx.x;
    if (idx >= N * 128) return;
    int n = idx >> 7, j = idx & 127;
    float acc = 0.f;
    for (int k = 0; k < K; ++k) acc += x[n * K + k] * W[k * 128 + j];
    out[idx] = acc;
}

// out[n][h] = sum_k x[n*K+k] * Q[k*4+h]
__global__ void k_alpha(const float* __restrict__ x, const float* __restrict__ Q,
                        float* __restrict__ out, int N, int K) {
    int idx = blockIdx.x * blockDim.x + threadIdx.x;
    if (idx >= N * 4) return;
    int n = idx >> 2, h = idx & 3;
    float acc = 0.f;
    for (int k = 0; k < K; ++k) acc += x[n * K + k] * Q[k * 4 + h];
    out[idx] = acc;
}

// fused: adA[n][h] = x@Qa, adB[n][h] = x@Qb  (one pass over x_tasks)
__global__ void k_alpha2(const float* __restrict__ x, const float* __restrict__ Qa,
                         const float* __restrict__ Qb, float* __restrict__ oa,
                         float* __restrict__ ob, int N, int K) {
    int idx = blockIdx.x * blockDim.x + threadIdx.x;
    if (idx >= N * 4) return;
    int n = idx >> 2, h = idx & 3;
    float a = 0.f, b = 0.f;
    for (int k = 0; k < K; ++k) {
        float v = x[n * K + k];
        a += v * Qa[k * 4 + h];
        b += v * Qb[k * 4 + h];
    }
    oa[idx] = a; ob[idx] = b;
}

// fused: as3[n][h] and ad3[n][h] from one pass over hs row
__global__ void k_alpha_from_h2(const float* __restrict__ hs, const float* __restrict__ As,
                                const float* __restrict__ Ad, float* __restrict__ oa,
                                float* __restrict__ ob, int N) {
    int idx = blockIdx.x * blockDim.x + threadIdx.x;
    if (idx >= N * 4) return;
    int n = idx >> 2, h = idx & 3;
    float a = 0.f, b = 0.f;
    #pragma unroll
    for (int c = 0; c < 32; ++c) {
        float v = hs[n * 128 + h * 32 + c];
        a += v * As[h * 32 + c];
        b += v * Ad[h * 32 + c];
    }
    oa[idx] = a; ob[idx] = b;
}

// degree histogram for all 3 graphs in one grid
__global__ void k_hist(const int* __restrict__ dt, const int* __restrict__ vt,
                       const int* __restrict__ tt, int* __restrict__ deg) {
    int e = blockIdx.x * blockDim.x + threadIdx.x;
    if (e < EDT) atomicAdd(&deg[dt[EDT + e]], 1);
    else if (e < EDT + EVT) atomicAdd(&deg[NT + vt[EVT + (e - EDT)]], 1);
    else if (e < EDT + EVT + ETT) atomicAdd(&deg[2 * NT + tt[ETT + (e - EDT - EVT)]], 1);
}

// scan phase A: per-tile block reduce -> bsum[75]; coalesced int4 loads
__global__ __launch_bounds__(256) void k_scan_part(const int* __restrict__ deg,
                                                   int* __restrict__ bsum) {
    int b = blockIdx.x;
    int g = b / SCAN_NB, t = b % SCAN_NB;
    int base = t * SCAN_TILE + threadIdx.x * 8;
    const int* dg = deg + (size_t)g * NT;
    int s = 0;
    if (base + 8 <= NT) {
        int4 a = *reinterpret_cast<const int4*>(dg + base);
        int4 c = *reinterpret_cast<const int4*>(dg + base + 4);
        s = a.x + a.y + a.z + a.w + c.x + c.y + c.z + c.w;
    } else {
        for (int i = 0; i < 8; ++i) if (base + i < NT) s += dg[base + i];
    }
    __shared__ int red[256];
    red[threadIdx.x] = s;
    __syncthreads();
    for (int off = 128; off > 0; off >>= 1) {
        if (threadIdx.x < off) red[threadIdx.x] += red[threadIdx.x + off];
        __syncthreads();
    }
    if (threadIdx.x == 0) bsum[b] = red[0];
}

// scan phase B: one wave; exclusive-scan the 25 tile sums of each graph; write graph totals
__global__ void k_scan_bsum(int* __restrict__ bsum, int* __restrict__ rp) {
    int lane = threadIdx.x;
    for (int g = 0; g < 3; ++g) {
        int v = (lane < SCAN_NB) ? bsum[g * SCAN_NB + lane] : 0;
        int inc = v;
        #pragma unroll
        for (int off = 1; off < 32; off <<= 1) {
            int o = __shfl_up(inc, off, 32);
            if ((lane & 31) >= off) inc += o;
        }
        if (lane < SCAN_NB) bsum[g * SCAN_NB + lane] = inc - v;
        if (lane == SCAN_NB - 1) rp[(size_t)g * (NT + 1) + NT] = inc;
    }
}

// scan phase C: per-tile exclusive scan + tile offset; writes rp and deg (bucket cursor)
__global__ __launch_bounds__(256) void k_scan_final(int* __restrict__ deg,
                                                    const int* __restrict__ bsum,
                                                    int* __restrict__ rp) {
    int b = blockIdx.x;
    int g = b / SCAN_NB, t = b % SCAN_NB;
    int tid = threadIdx.x;
    int base = t * SCAN_TILE + tid * 8;
    int* dg = deg + (size_t)g * NT;
    int* rpg = rp + (size_t)g * (NT + 1);
    int v[8];
    int s = 0;
    if (base + 8 <= NT) {
        int4 a = *reinterpret_cast<const int4*>(dg + base);
        int4 c = *reinterpret_cast<const int4*>(dg + base + 4);
        v[0] = a.x; v[1] = a.y; v[2] = a.z; v[3] = a.w;
        v[4] = c.x; v[5] = c.y; v[6] = c.z; v[7] = c.w;
        s = v[0] + v[1] + v[2] + v[3] + v[4] + v[5] + v[6] + v[7];
    } else {
        #pragma unroll
        for (int i = 0; i < 8; ++i) {
            v[i] = (base + i < NT) ? dg[base + i] : 0;
            s += v[i];
        }
    }
    __shared__ int sums[256];
    sums[tid] = s;
    __syncthreads();
    for (int off = 1; off < 256; off <<= 1) {
        int x = (tid >= off) ? sums[tid - off] : 0;
        __syncthreads();
        sums[tid] += x;
        __syncthreads();
    }
    int run = bsum[b] + (tid ? sums[tid - 1] : 0);
    #pragma unroll
    for (int i = 0; i < 8; ++i) {
        int idx = base + i;
        if (idx < NT) { rpg[idx] = run; dg[idx] = run; run += v[i]; }
    }
}

// fused: per-edge attention exp + bucket into CSR slots (conv1/conv2)
__global__ void k_edge_bucket(const int* __restrict__ src, const int* __restrict__ dst,
                              const float* __restrict__ ea, int E, int KE,
                              const float* __restrict__ P, const float* __restrict__ as_,
                              const float* __restrict__ ad_,
                              int* __restrict__ cur, int* __restrict__ esrc,
                              float* __restrict__ wv) {
    int e = blockIdx.x * blockDim.x + threadIdx.x;
    if (e >= E) return;
    int s = src[e], d = dst[e];
    float al[4];
    #pragma unroll
    for (int h = 0; h < 4; ++h) al[h] = as_[s * 4 + h] + ad_[d * 4 + h];
    for (int k = 0; k < KE; ++k) {
        float v = ea[e * KE + k];
        #pragma unroll
        for (int h = 0; h < 4; ++h) al[h] += v * P[k * 4 + h];
    }
    int slot = atomicAdd(&cur[d], 1);
    esrc[slot] = s;
    float4 w4 = make_float4(expf(lrelu(al[0])), expf(lrelu(al[1])),
                            expf(lrelu(al[2])), expf(lrelu(al[3])));
    *reinterpret_cast<float4*>(&wv[(size_t)slot * 4]) = w4;
}

// conv3 variant: also stores the edge-attr logit part ae (needed for self-loop mean)
__global__ void k_edge_bucket_c3(const int* __restrict__ src, const int* __restrict__ dst,
                                 const float* __restrict__ ea, const float* __restrict__ P,
                                 const float* __restrict__ as_, const float* __restrict__ ad_,
                                 int* __restrict__ cur, int* __restrict__ esrc,
                                 float* __restrict__ wv) {
    int e = blockIdx.x * blockDim.x + threadIdx.x;
    if (e >= ETT) return;
    int s = src[e], d = dst[e];
    float ae[4] = {0.f, 0.f, 0.f, 0.f};
    #pragma unroll
    for (int k = 0; k < 4; ++k) {
        float v = ea[e * 4 + k];
        #pragma unroll
        for (int h = 0; h < 4; ++h) ae[h] += v * P[k * 4 + h];
    }
    int slot = atomicAdd(&cur[d], 1);
    esrc[slot] = s;
    float4 x4 = make_float4(expf(lrelu(as_[s * 4 + 0] + ad_[d * 4 + 0] + ae[0])),
                            expf(lrelu(as_[s * 4 + 1] + ad_[d * 4 + 1] + ae[1])),
                            expf(lrelu(as_[s * 4 + 2] + ad_[d * 4 + 2] + ae[2])),
                            expf(lrelu(as_[s * 4 + 3] + ad_[d * 4 + 3] + ae[3])));
    *reinterpret_cast<float4*>(&wv[(size_t)slot * 8]) = x4;
    *reinterpret_cast<float4*>(&wv[(size_t)slot * 8 + 4]) = make_float4(ae[0], ae[1], ae[2], ae[3]);
}

// CSR gather conv1/conv2: 32 lanes per dst, float4 per lane, edge loop unrolled x4 (MLP).
__global__ __launch_bounds__(256) void k_gather12(const int* __restrict__ rp,
                                                  const int* __restrict__ esrc,
                                                  const float* __restrict__ wv,
                                                  const float* __restrict__ hs,
                                                  const float* __restrict__ bias,
                                                  float* __restrict__ tasks, int cbase) {
    int tid = threadIdx.x;
    int d = blockIdx.x * 8 + (tid >> 5);
    int lane = tid & 31;
    int h = lane >> 3;
    int i0 = rp[d], i1 = rp[d + 1];
    float ax = 0.f, ay = 0.f, az = 0.f, aw = 0.f, den = 0.f;
    int i = i0;
    for (; i + 4 <= i1; i += 4) {
        int s0 = esrc[i], s1 = esrc[i + 1], s2 = esrc[i + 2], s3 = esrc[i + 3];
        float w0 = wv[(size_t)i * 4 + h];
        float w1 = wv[(size_t)(i + 1) * 4 + h];
        float w2 = wv[(size_t)(i + 2) * 4 + h];
        float w3 = wv[(size_t)(i + 3) * 4 + h];
        float4 v0 = *reinterpret_cast<const float4*>(&hs[(size_t)s0 * 128 + lane * 4]);
        float4 v1 = *reinterpret_cast<const float4*>(&hs[(size_t)s1 * 128 + lane * 4]);
        float4 v2 = *reinterpret_cast<const float4*>(&hs[(size_t)s2 * 128 + lane * 4]);
        float4 v3 = *reinterpret_cast<const float4*>(&hs[(size_t)s3 * 128 + lane * 4]);
        ax += v0.x * w0 + v1.x * w1 + v2.x * w2 + v3.x * w3;
        ay += v0.y * w0 + v1.y * w1 + v2.y * w2 + v3.y * w3;
        az += v0.z * w0 + v1.z * w1 + v2.z * w2 + v3.z * w3;
        aw += v0.w * w0 + v1.w * w1 + v2.w * w2 + v3.w * w3;
        den += w0 + w1 + w2 + w3;
    }
    for (; i < i1; ++i) {
        int s = esrc[i];
        float w = wv[(size_t)i * 4 + h];
        float4 v = *reinterpret_cast<const float4*>(&hs[(size_t)s * 128 + lane * 4]);
        ax += v.x * w; ay += v.y * w; az += v.z * w; aw += v.w * w;
        den += w;
    }
    float4 b4 = *reinterpret_cast<const float4*>(&bias[lane * 4]);
    float r = 1.f / (den + 1e-16f);
    float4 o = make_float4(fmaxf(ax * r + b4.x, 0.f), fmaxf(ay * r + b4.y, 0.f),
                           fmaxf(az * r + b4.z, 0.f), fmaxf(aw * r + b4.w, 0.f));
    *reinterpret_cast<float4*>(&tasks[(size_t)d * 256 + cbase + lane * 4]) = o;
}

// CSR gather conv3: 32 lanes/dst, per-head denominators, edge loop unrolled x2,
// self-loop (mean edge-attr) message, head-mean, +b3, relu fused. Writes d_out once.
__global__ __launch_bounds__(256) void k_gather_c3(const int* __restrict__ rp,
                                                   const int* __restrict__ esrc,
                                                   const float* __restrict__ wv,
                                                   const float* __restrict__ hs,
                                                   const float* __restrict__ as3,
                                                   const float* __restrict__ ad3,
                                                   const float* __restrict__ b3,
                                                   float* __restrict__ out) {
    int tid = threadIdx.x;
    int d = blockIdx.x * 8 + (tid >> 5);
    int c = tid & 31;
    int i0 = rp[d], i1 = rp[d + 1];
    float acc[4] = {0.f, 0.f, 0.f, 0.f};
    float den[4] = {0.f, 0.f, 0.f, 0.f};
    float aes[4] = {0.f, 0.f, 0.f, 0.f};
    int i = i0;
    for (; i + 2 <= i1; i += 2) {
        int s0 = esrc[i], s1 = esrc[i + 1];
        float4 x0 = *reinterpret_cast<const float4*>(&wv[(size_t)i * 8]);
        float4 a0 = *reinterpret_cast<const float4*>(&wv[(size_t)i * 8 + 4]);
        float4 x1 = *reinterpret_cast<const float4*>(&wv[(size_t)(i + 1) * 8]);
        float4 a1 = *reinterpret_cast<const float4*>(&wv[(size_t)(i + 1) * 8 + 4]);
        const float* h0 = hs + (size_t)s0 * 128 + c;
        const float* h1 = hs + (size_t)s1 * 128 + c;
        acc[0] += x0.x * h0[0]  + x1.x * h1[0];
        acc[1] += x0.y * h0[32] + x1.y * h1[32];
        acc[2] += x0.z * h0[64] + x1.z * h1[64];
        acc[3] += x0.w * h0[96] + x1.w * h1[96];
        den[0] += x0.x + x1.x; den[1] += x0.y + x1.y;
        den[2] += x0.z + x1.z; den[3] += x0.w + x1.w;
        aes[0] += a0.x + a1.x; aes[1] += a0.y + a1.y;
        aes[2] += a0.z + a1.z; aes[3] += a0.w + a1.w;
    }
    for (; i < i1; ++i) {
        int s = esrc[i];
        float4 x4 = *reinterpret_cast<const float4*>(&wv[(size_t)i * 8]);
        float4 a4 = *reinterpret_cast<const float4*>(&wv[(size_t)i * 8 + 4]);
        const float* hrow = hs + (size_t)s * 128 + c;
        acc[0] += x4.x * hrow[0];  acc[1] += x4.y * hrow[32];
        acc[2] += x4.z * hrow[64]; acc[3] += x4.w * hrow[96];
        den[0] += x4.x; den[1] += x4.y; den[2] += x4.z; den[3] += x4.w;
        aes[0] += a4.x; aes[1] += a4.y; aes[2] += a4.z; aes[3] += a4.w;
    }
    float inv = 1.f / fmaxf((float)(i1 - i0), 1.f);
    const float* hd = hs + (size_t)d * 128 + c;
    float o = 0.f;
    #pragma unroll
    for (int h = 0; h < 4; ++h) {
        float m = aes[h] * inv;
        float exl = expf(lrelu(as3[d * 4 + h] + ad3[d * 4 + h] + m));
        float a = acc[h] + exl * hd[h * 32];
        o += a / (den[h] + exl + 1e-16f);
    }
    o = 0.25f * o + b3[c];
    out[(size_t)d * 32 + c] = o > 0.f ? o : 0.f;
}

// hs3 = tasks[50000,256] @ W3[256,128] via bf16 split MFMA:
// A*B ~= Ah*Bh + Ah*Bl + Al*Bh (error ~2^-16 rel). 4 waves/block, 2 strips(16rows)/wave.
// B (w3 hi/lo, [n][k] bf16) staged per K-half in LDS with XOR-chunk swizzle.
__global__ __launch_bounds__(256, 2) void k_gemm_mfma(const float* __restrict__ T,
                                                      const unsigned short* __restrict__ w3hT,
                                                      const unsigned short* __restrict__ w3lT,
                                                      float* __restrict__ outp) {
    __shared__ uint4 sB[2][2048];      // [hi/lo][128 cols x 16 chunks], 64 KiB
    int tid = threadIdx.x;
    int lane = tid & 63;
    int wid = tid >> 6;
    int arow = lane & 15;              // A row within strip / out col within tile
    int kgrp = lane >> 4;              // 0..3
    int s0 = blockIdx.x * 8 + wid * 2; // first of 2 strips for this wave
    int ss0 = s0 < 3125 ? s0 : 3124;
    int ss1 = (s0 + 1) < 3125 ? (s0 + 1) : 3124;
    const uint4* w3h4 = reinterpret_cast<const uint4*>(w3hT);
    const uint4* w3l4 = reinterpret_cast<const uint4*>(w3lT);

    v4f acc[2][8];
    #pragma unroll
    for (int sp = 0; sp < 2; ++sp)
        #pragma unroll
        for (int nt = 0; nt < 8; ++nt) acc[sp][nt] = (v4f)0.f;

    #pragma unroll
    for (int kt = 0; kt < 2; ++kt) {
        __syncthreads();               // previous half's LDS reads complete
        // issue A loads for this K-half (in flight across staging)
        float4 a0[8], a1[8];
        const float* Ta0 = T + (size_t)(ss0 * 16 + arow) * 256 + kt * 128 + kgrp * 8;
        const float* Ta1 = T + (size_t)(ss1 * 16 + arow) * 256 + kt * 128 + kgrp * 8;
        #pragma unroll
        for (int kc = 0; kc < 4; ++kc) {
            a0[kc * 2]     = *reinterpret_cast<const float4*>(Ta0 + kc * 32);
            a0[kc * 2 + 1] = *reinterpret_cast<const float4*>(Ta0 + kc * 32 + 4);
            a1[kc * 2]     = *reinterpret_cast<const float4*>(Ta1 + kc * 32);
            a1[kc * 2 + 1] = *reinterpret_cast<const float4*>(Ta1 + kc * 32 + 4);
        }
        // stage B half: [128n][16 chunks of 8 bf16], chunk index XOR-swizzled by n&7
        #pragma unroll
        for (int it = 0; it < 8; ++it) {
            int c = it * 256 + tid;            // 0..2047
            int n = c >> 4, ch = c & 15;
            int gi = n * 32 + kt * 16 + ch;
            int li = n * 16 + (ch ^ (n & 7));
            sB[0][li] = w3h4[gi];
            sB[1][li] = w3l4[gi];
        }
        __syncthreads();
        #pragma unroll
        for (int kc = 0; kc < 4; ++kc) {
            v8s ah0, al0, ah1, al1;
            cvt_split(a0[kc * 2], a0[kc * 2 + 1], ah0, al0);
            cvt_split(a1[kc * 2], a1[kc * 2 + 1], ah1, al1);
            #pragma unroll
            for (int nt = 0; nt < 8; ++nt) {
                int col = nt * 16 + arow;
                int ch = kc * 4 + kgrp;
                int li = col * 16 + (ch ^ (col & 7));
                v8s bh = *reinterpret_cast<const v8s*>(&sB[0][li]);
                v8s bl = *reinterpret_cast<const v8s*>(&sB[1][li]);
                acc[0][nt] = __builtin_amdgcn_mfma_f32_16x16x32_bf16(ah0, bh, acc[0][nt], 0, 0, 0);
                acc[0][nt] = __builtin_amdgcn_mfma_f32_16x16x32_bf16(ah0, bl, acc[0][nt], 0, 0, 0);
                acc[0][nt] = __builtin_amdgcn_mfma_f32_16x16x32_bf16(al0, bh, acc[0][nt], 0, 0, 0);
                acc[1][nt] = __builtin_amdgcn_mfma_f32_16x16x32_bf16(ah1, bh, acc[1][nt], 0, 0, 0);
                acc[1][nt] = __builtin_amdgcn_mfma_f32_16x16x32_bf16(ah1, bl, acc[1][nt], 0, 0, 0);
                acc[1][nt] = __builtin_amdgcn_mfma_f32_16x16x32_bf16(al1, bh, acc[1][nt], 0, 0, 0);
            }
        }
    }
    // C layout: col = lane&15, row = (lane>>4)*4 + reg
    if (s0 < 3125) {
        #pragma unroll
        for (int nt = 0; nt < 8; ++nt)
            #pragma unroll
            for (int i = 0; i < 4; ++i)
                outp[(size_t)(s0 * 16 + kgrp * 4 + i) * 128 + nt * 16 + arow] = acc[0][nt][i];
    }
    if (s0 + 1 < 3125) {
        #pragma unroll
        for (int nt = 0; nt < 8; ++nt)
            #pragma unroll
            for (int i = 0; i < 4; ++i)
                outp[(size_t)((s0 + 1) * 16 + kgrp * 4 + i) * 128 + nt * 16 + arow] = acc[1][nt][i];
    }
}

extern "C" void kernel_launch(void* const* d_in, const int* in_sizes, int n_in,
                              void* d_out, int out_size, void* d_ws, size_t ws_size,
                              hipStream_t stream) {
    const float* x_data  = (const float*)d_in[0];
    const float* x_tasks = (const float*)d_in[1];
    const float* x_dev   = (const float*)d_in[2];
    const int*   ei_dt   = (const int*)d_in[3];
    const float* ea_dt   = (const float*)d_in[4];
    const int*   ei_vt   = (const int*)d_in[5];
    const float* ea_vt   = (const float*)d_in[6];
    const int*   ei_tt   = (const int*)d_in[7];
    const float* ea_tt   = (const float*)d_in[8];
    const float* Ws1 = (const float*)d_in[9];  const float* Wd1 = (const float*)d_in[10];
    const float* We1 = (const float*)d_in[11]; const float* As1 = (const float*)d_in[12];
    const float* Ad1 = (const float*)d_in[13]; const float* Ae1 = (const float*)d_in[14];
    const float* b1  = (const float*)d_in[15];
    const float* Ws2 = (const float*)d_in[16]; const float* Wd2 = (const float*)d_in[17];
    const float* We2 = (const float*)d_in[18]; const float* As2 = (const float*)d_in[19];
    const float* Ad2 = (const float*)d_in[20]; const float* Ae2 = (const float*)d_in[21];
    const float* b2  = (const float*)d_in[22];
    const float* W3  = (const float*)d_in[23]; const float* We3 = (const float*)d_in[24];
    const float* As3 = (const float*)d_in[25]; const float* Ad3 = (const float*)d_in[26];
    const float* Ae3 = (const float*)d_in[27]; const float* b3  = (const float*)d_in[28];

    if (ws_size < WS_TOTAL * sizeof(float)) return;

    float* w = (float*)d_ws;
    float* tasks = w + OFF_TASKS;
    float* hs    = w + OFF_HS;                 // hs1 (conv1) then hs3 (conv3)
    int*   esrc1 = (int*)(w + OFF_ESRC1);
    int*   esrc2 = (int*)(w + OFF_ESRC2);
    float* wv1   = w + OFF_WV1;
    float* wv3   = w + OFF_WV1;                // aliases wv1 (dead by conv3)
    float* wv2   = w + OFF_WV2;
    int*   esrc3 = (int*)(w + OFF_WV2);        // aliases wv2 (dead by conv3)
    int*   deg   = (int*)(w + OFF_DEG);        // also bucket cursor after scan
    int*   rp    = (int*)(w + OFF_RP);
    int*   bsum  = (int*)(w + OFF_BSUM);
    unsigned short* w3hT = (unsigned short*)(w + OFF_W3HT);
    unsigned short* w3lT = (unsigned short*)(w + OFF_W3LT);
    float* as1 = w + OFF_AS1;
    float* ad1 = w + OFF_AD1; float* as3 = w + OFF_AD1;   // as3 aliases ad1
    float* ad2 = w + OFF_AD2; float* ad3 = w + OFF_AD2;   // ad3 aliases ad2
    float* hs2 = w + OFF_HS2; float* as2 = w + OFF_AS2;
    float* Qs1 = w + OFF_QS1; float* Qd1 = w + OFF_QD1; float* P1 = w + OFF_P1;
    float* Qs2 = w + OFF_QS2; float* Qd2 = w + OFF_QD2; float* P2 = w + OFF_P2;
    float* P3  = w + OFF_P3;
    float* out = (float*)d_out;

    dim3 B(256);
    #define GRID(n) dim3((unsigned)(((n) + 255) / 256))

    // CSR prep: zero degrees, histogram, hierarchical scan (rp + cursor copy in deg)
    hipMemsetAsync(deg, 0, 3 * NT * sizeof(int), stream);
    k_proj_small<<<1, 320, 0, stream>>>(Ws1, As1, Wd1, Ad1, We1, Ae1,
                                        Ws2, As2, Wd2, Ad2, We2, Ae2, We3, Ae3,
                                        Qs1, Qd1, P1, Qs2, Qd2, P2, P3);
    k_w3split<<<GRID(256 * 128), B, 0, stream>>>(W3, w3hT, w3lT);
    k_hist<<<GRID(EDT + EVT + ETT), B, 0, stream>>>(ei_dt, ei_vt, ei_tt, deg);
    k_scan_part<<<dim3(3 * SCAN_NB), B, 0, stream>>>(deg, bsum);
    k_scan_bsum<<<1, 64, 0, stream>>>(bsum, rp);
    k_scan_final<<<dim3(3 * SCAN_NB), B, 0, stream>>>(deg, bsum, rp);

    // conv1 + conv2 inputs
    k_linproj<<<GRID(NDAT * 128), B, 0, stream>>>(x_data, Ws1, hs, NDAT, 8);
    k_alpha<<<GRID(NDAT * 4), B, 0, stream>>>(x_data, Qs1, as1, NDAT, 8);
    k_alpha2<<<GRID(NT * 4), B, 0, stream>>>(x_tasks, Qd1, Qd2, ad1, ad2, NT, 16);
    k_edge_bucket<<<GRID(EDT), B, 0, stream>>>(ei_dt, ei_dt + EDT, ea_dt, EDT, 8,
                                               P1, as1, ad1, deg, esrc1, wv1);
    k_linproj<<<GRID(NDEV * 128), B, 0, stream>>>(x_dev, Ws2, hs2, NDEV, 8);
    k_alpha<<<GRID(NDEV * 4), B, 0, stream>>>(x_dev, Qs2, as2, NDEV, 8);
    k_edge_bucket<<<GRID(EVT), B, 0, stream>>>(ei_vt, ei_vt + EVT, ea_vt, EVT, 6,
                                               P2, as2, ad2, deg + NT, esrc2, wv2);
    // gathers (write tasks fully, bias+relu fused)
    k_gather12<<<dim3(NT / 8), B, 0, stream>>>(rp, esrc1, wv1, hs, b1, tasks, 0);
    k_gather12<<<dim3(NT / 8), B, 0, stream>>>(rp + (NT + 1), esrc2, wv2, hs2, b2, tasks, 128);

    // conv3: tasks -> tasks
    k_gemm_mfma<<<dim3(391), dim3(256), 0, stream>>>(tasks, w3hT, w3lT, hs);
    k_alpha_from_h2<<<GRID(NT * 4), B, 0, stream>>>(hs, As3, Ad3, as3, ad3, NT);
    k_edge_bucket_c3<<<GRID(ETT), B, 0, stream>>>(ei_tt, ei_tt + ETT, ea_tt, P3,
                                                  as3, ad3, deg + 2 * NT, esrc3, wv3);
    k_gather_c3<<<dim3(NT / 8), B, 0, stream>>>(rp + 2 * (NT + 1), esrc3, wv3, hs,
                                                as3, ad3, b3, out);
    #undef GRID
}

// Round 6
// 320.486 us; speedup vs baseline: 3.2112x; 1.0333x over previous
//
#include <hip/hip_runtime.h>
#include <math.h>

static const int NT = 50000, NDAT = 20000, NDEV = 4;
static const int EDT = 800000, EVT = 200000, ETT = 400000;

// scan geometry: 3 graphs x 25 tiles of 2048 (256 thr x 8 elems)
static const int SCAN_TILE = 2048, SCAN_NB = 25;

// ---------------- workspace layout (float offsets), liveness-aliased ----------------
static const size_t OFF_TASKS = 0;                   // 12,800,000  [NT,256] fp32
static const size_t OFF_HS    = 12800000;            //  6,400,000  hs1 (2.56M) then hs3 (6.4M)
static const size_t OFF_RANK  = OFF_HS + 2560000;    //  1,400,000  ints (dead before gemm writes hs3)
static const size_t OFF_PERM1 = 19200000;            //  1,600,000  int2[EDT]
static const size_t OFF_PERM2 = 20800000;            //    400,000  int2[EVT]
static const size_t OFF_PERM3 = 21200000;            //    800,000  int2[ETT]
static const size_t OFF_DEG   = 23200000;            //    150,000  3 x NT ints
static const size_t OFF_RP    = 23350000;            //    150,003  3 x (NT+1) ints
static const size_t OFF_AS1   = 23500004;            //     80,000
static const size_t OFF_AD1   = 23580004;            //    200,000  as3 reuses
static const size_t OFF_AD2   = 23780004;            //    200,000  ad3 reuses
static const size_t OFF_HS2   = 23980004;            //        512
static const size_t OFF_AS2   = 23980516;            //         16
static const size_t OFF_QS1   = 23980532;            //         32
static const size_t OFF_QD1   = 23980564;            //         64
static const size_t OFF_P1    = 23980628;            //         32
static const size_t OFF_QS2   = 23980660;            //         32
static const size_t OFF_QD2   = 23980692;            //         64
static const size_t OFF_P2    = 23980756;            //         24
static const size_t OFF_P3    = 23980780;            //         16
static const size_t OFF_BSUM  = 23980796;            //        128 ints (75 used)
static const size_t OFF_W3HT  = 23980924;            //     16,384 (32768 ushorts, [128n][256k])
static const size_t OFF_W3LT  = 23997308;            //     16,384
static const size_t WS_TOTAL  = 24013692;            // floats (~96 MiB)

typedef short v8s __attribute__((ext_vector_type(8)));
typedef float v4f __attribute__((ext_vector_type(4)));

__device__ __forceinline__ float lrelu(float a) { return a > 0.f ? a : 0.2f * a; }
__device__ __forceinline__ unsigned short f2bf(float x) {
    unsigned int u = __float_as_uint(x);
    return (unsigned short)((u + 0x7FFFu + ((u >> 16) & 1u)) >> 16);
}
__device__ __forceinline__ float bf2f(unsigned short h) {
    return __uint_as_float(((unsigned int)h) << 16);
}
__device__ __forceinline__ void cvt_split(const float4& A, const float4& B, v8s& hi, v8s& lo) {
    union { unsigned short u[8]; v8s v; } H, L;
    float f[8] = {A.x, A.y, A.z, A.w, B.x, B.y, B.z, B.w};
    #pragma unroll
    for (int i = 0; i < 8; ++i) {
        unsigned short h = f2bf(f[i]);
        H.u[i] = h;
        L.u[i] = f2bf(f[i] - bf2f(h));
    }
    hi = H.v; lo = L.v;
}

// Q[k][h] = sum_c W[k*128 + h*32 + c] * A[h*32 + c], for all 7 small matrices
__global__ void k_proj_small(const float* Ws1, const float* As1,
                             const float* Wd1, const float* Ad1,
                             const float* We1, const float* Ae1,
                             const float* Ws2, const float* As2,
                             const float* Wd2, const float* Ad2,
                             const float* We2, const float* Ae2,
                             const float* We3, const float* Ae3,
                             float* Qs1, float* Qd1, float* P1,
                             float* Qs2, float* Qd2, float* P2, float* P3) {
    int t = threadIdx.x;
    const float *W, *A; float* O; int u;
    if      (t < 32)  { W = Ws1; A = As1; O = Qs1; u = t; }
    else if (t < 96)  { W = Wd1; A = Ad1; O = Qd1; u = t - 32; }
    else if (t < 128) { W = We1; A = Ae1; O = P1;  u = t - 96; }
    else if (t < 160) { W = Ws2; A = As2; O = Qs2; u = t - 128; }
    else if (t < 224) { W = Wd2; A = Ad2; O = Qd2; u = t - 160; }
    else if (t < 248) { W = We2; A = Ae2; O = P2;  u = t - 224; }
    else if (t < 264) { W = We3; A = Ae3; O = P3;  u = t - 248; }
    else return;
    int k = u >> 2, h = u & 3;
    float acc = 0.f;
    for (int c = 0; c < 32; ++c) acc += W[k * 128 + h * 32 + c] * A[h * 32 + c];
    O[k * 4 + h] = acc;
}

// one-time: split W3[256,128] into bf16 hi/lo, transposed to [128n][256k]
__global__ void k_w3split(const float* __restrict__ W3, unsigned short* __restrict__ hiT,
                          unsigned short* __restrict__ loT) {
    int idx = blockIdx.x * blockDim.x + threadIdx.x;
    if (idx >= 256 * 128) return;
    int k = idx >> 7, n = idx & 127;
    float x = W3[idx];
    unsigned short h = f2bf(x);
    hiT[n * 256 + k] = h;
    loT[n * 256 + k] = f2bf(x - bf2f(h));
}

// out[n][j] = sum_k x[n*K+k] * W[k*128+j]
__global__ void k_linproj(const float* __restrict__ x, const float* __restrict__ W,
                          float* __restrict__ out, int N, int K) {
    int idx = blockIdx.x * blockDim.x + threadIdx.x;
    if (idx >= N * 128) return;
    int n = idx >> 7, j = idx & 127;
    float acc = 0.f;
    for (int k = 0; k < K; ++k) acc += x[n * K + k] * W[k * 128 + j];
    out[idx] = acc;
}

// out[n][h] = sum_k x[n*K+k] * Q[k*4+h]
__global__ void k_alpha(const float* __restrict__ x, const float* __restrict__ Q,
                        float* __restrict__ out, int N, int K) {
    int idx = blockIdx.x * blockDim.x + threadIdx.x;
    if (idx >= N * 4) return;
    int n = idx >> 2, h = idx & 3;
    float acc = 0.f;
    for (int k = 0; k < K; ++k) acc += x[n * K + k] * Q[k * 4 + h];
    out[idx] = acc;
}

// fused: adA[n][h] = x@Qa, adB[n][h] = x@Qb  (one pass over x_tasks)
__global__ void k_alpha2(const float* __restrict__ x, const float* __restrict__ Qa,
                         const float* __restrict__ Qb, float* __restrict__ oa,
                         float* __restrict__ ob, int N, int K) {
    int idx = blockIdx.x * blockDim.x + threadIdx.x;
    if (idx >= N * 4) return;
    int n = idx >> 2, h = idx & 3;
    float a = 0.f, b = 0.f;
    for (int k = 0; k < K; ++k) {
        float v = x[n * K + k];
        a += v * Qa[k * 4 + h];
        b += v * Qb[k * 4 + h];
    }
    oa[idx] = a; ob[idx] = b;
}

// fused: as3[n][h] and ad3[n][h] from one pass over hs row
__global__ void k_alpha_from_h2(const float* __restrict__ hs, const float* __restrict__ As,
                                const float* __restrict__ Ad, float* __restrict__ oa,
                                float* __restrict__ ob, int N) {
    int idx = blockIdx.x * blockDim.x + threadIdx.x;
    if (idx >= N * 4) return;
    int n = idx >> 2, h = idx & 3;
    float a = 0.f, b = 0.f;
    #pragma unroll
    for (int c = 0; c < 32; ++c) {
        float v = hs[n * 128 + h * 32 + c];
        a += v * As[h * 32 + c];
        b += v * Ad[h * 32 + c];
    }
    oa[idx] = a; ob[idx] = b;
}

// degree histogram for all 3 graphs; also records each edge's rank within its dst
__global__ void k_hist(const int* __restrict__ dt, const int* __restrict__ vt,
                       const int* __restrict__ tt, int* __restrict__ deg,
                       int* __restrict__ rank) {
    int e = blockIdx.x * blockDim.x + threadIdx.x;
    if (e < EDT) rank[e] = atomicAdd(&deg[dt[EDT + e]], 1);
    else if (e < EDT + EVT) rank[e] = atomicAdd(&deg[NT + vt[EVT + (e - EDT)]], 1);
    else if (e < EDT + EVT + ETT) rank[e] = atomicAdd(&deg[2 * NT + tt[ETT + (e - EDT - EVT)]], 1);
}

// scan phase A: per-tile block reduce -> bsum[75]; coalesced int4 loads
__global__ __launch_bounds__(256) void k_scan_part(const int* __restrict__ deg,
                                                   int* __restrict__ bsum) {
    int b = blockIdx.x;
    int g = b / SCAN_NB, t = b % SCAN_NB;
    int base = t * SCAN_TILE + threadIdx.x * 8;
    const int* dg = deg + (size_t)g * NT;
    int s = 0;
    if (base + 8 <= NT) {
        int4 a = *reinterpret_cast<const int4*>(dg + base);
        int4 c = *reinterpret_cast<const int4*>(dg + base + 4);
        s = a.x + a.y + a.z + a.w + c.x + c.y + c.z + c.w;
    } else {
        for (int i = 0; i < 8; ++i) if (base + i < NT) s += dg[base + i];
    }
    __shared__ int red[256];
    red[threadIdx.x] = s;
    __syncthreads();
    for (int off = 128; off > 0; off >>= 1) {
        if (threadIdx.x < off) red[threadIdx.x] += red[threadIdx.x + off];
        __syncthreads();
    }
    if (threadIdx.x == 0) bsum[b] = red[0];
}

// scan phase B: one wave; exclusive-scan the 25 tile sums of each graph; write graph totals
__global__ void k_scan_bsum(int* __restrict__ bsum, int* __restrict__ rp) {
    int lane = threadIdx.x;
    for (int g = 0; g < 3; ++g) {
        int v = (lane < SCAN_NB) ? bsum[g * SCAN_NB + lane] : 0;
        int inc = v;
        #pragma unroll
        for (int off = 1; off < 32; off <<= 1) {
            int o = __shfl_up(inc, off, 32);
            if ((lane & 31) >= off) inc += o;
        }
        if (lane < SCAN_NB) bsum[g * SCAN_NB + lane] = inc - v;
        if (lane == SCAN_NB - 1) rp[(size_t)g * (NT + 1) + NT] = inc;
    }
}

// scan phase C: per-tile exclusive scan + tile offset; writes rp
__global__ __launch_bounds__(256) void k_scan_final(const int* __restrict__ deg,
                                                    const int* __restrict__ bsum,
                                                    int* __restrict__ rp) {
    int b = blockIdx.x;
    int g = b / SCAN_NB, t = b % SCAN_NB;
    int tid = threadIdx.x;
    int base = t * SCAN_TILE + tid * 8;
    const int* dg = deg + (size_t)g * NT;
    int* rpg = rp + (size_t)g * (NT + 1);
    int v[8];
    int s = 0;
    if (base + 8 <= NT) {
        int4 a = *reinterpret_cast<const int4*>(dg + base);
        int4 c = *reinterpret_cast<const int4*>(dg + base + 4);
        v[0] = a.x; v[1] = a.y; v[2] = a.z; v[3] = a.w;
        v[4] = c.x; v[5] = c.y; v[6] = c.z; v[7] = c.w;
        s = v[0] + v[1] + v[2] + v[3] + v[4] + v[5] + v[6] + v[7];
    } else {
        #pragma unroll
        for (int i = 0; i < 8; ++i) {
            v[i] = (base + i < NT) ? dg[base + i] : 0;
            s += v[i];
        }
    }
    __shared__ int sums[256];
    sums[tid] = s;
    __syncthreads();
    for (int off = 1; off < 256; off <<= 1) {
        int x = (tid >= off) ? sums[tid - off] : 0;
        __syncthreads();
        sums[tid] += x;
        __syncthreads();
    }
    int run = bsum[b] + (tid ? sums[tid - 1] : 0);
    #pragma unroll
    for (int i = 0; i < 8; ++i) {
        int idx = base + i;
        if (idx < NT) { rpg[idx] = run; run += v[i]; }
    }
}

// bucket pass: only {src, edge-id} (8B) per slot; no atomics (slot = rp[d] + rank[e])
__global__ void k_permute(const int* __restrict__ dt, const int* __restrict__ vt,
                          const int* __restrict__ tt, const int* __restrict__ rank,
                          const int* __restrict__ rp, int2* __restrict__ p1,
                          int2* __restrict__ p2, int2* __restrict__ p3) {
    int e = blockIdx.x * blockDim.x + threadIdx.x;
    if (e < EDT) {
        int d = dt[EDT + e];
        p1[rp[d] + rank[e]] = make_int2(dt[e], e);
    } else if (e < EDT + EVT) {
        int ee = e - EDT;
        int d = vt[EVT + ee];
        p2[rp[(NT + 1) + d] + rank[e]] = make_int2(vt[ee], ee);
    } else if (e < EDT + EVT + ETT) {
        int ee = e - EDT - EVT;
        int d = tt[ETT + ee];
        p3[rp[2 * (NT + 1) + d] + rank[e]] = make_int2(tt[ee], ee);
    }
}

template<int KE>
__device__ __forceinline__ void load_ea(const float* __restrict__ ea, int e, float* v) {
    if (KE == 8) {
        float4 a = *reinterpret_cast<const float4*>(ea + (size_t)e * 8);
        float4 b = *reinterpret_cast<const float4*>(ea + (size_t)e * 8 + 4);
        v[0] = a.x; v[1] = a.y; v[2] = a.z; v[3] = a.w;
        v[4] = b.x; v[5] = b.y; v[6] = b.z; v[7] = b.w;
    } else {
        float2 a = *reinterpret_cast<const float2*>(ea + (size_t)e * 6);
        float2 b = *reinterpret_cast<const float2*>(ea + (size_t)e * 6 + 2);
        float2 c = *reinterpret_cast<const float2*>(ea + (size_t)e * 6 + 4);
        v[0] = a.x; v[1] = a.y; v[2] = b.x; v[3] = b.y; v[4] = c.x; v[5] = c.y;
    }
}

// CSR gather conv1/conv2 with in-register attention recompute.
// 32 lanes/dst (4 channels each via float4); edge loop unrolled x4 for MLP.
template<int KE>
__global__ __launch_bounds__(256) void k_gather12(const int* __restrict__ rp,
                                                  const int2* __restrict__ perm,
                                                  const float* __restrict__ as_,
                                                  const float* __restrict__ ad_,
                                                  const float* __restrict__ P,
                                                  const float* __restrict__ ea,
                                                  const float* __restrict__ hs,
                                                  const float* __restrict__ bias,
                                                  float* __restrict__ tasks, int cbase) {
    int tid = threadIdx.x;
    int d = blockIdx.x * 8 + (tid >> 5);
    int lane = tid & 31;
    int h = lane >> 3;
    float Pk[KE];
    #pragma unroll
    for (int k = 0; k < KE; ++k) Pk[k] = P[k * 4 + h];
    float base = ad_[d * 4 + h];
    int i0 = rp[d], i1 = rp[d + 1];
    float ax = 0.f, ay = 0.f, az = 0.f, aw = 0.f, den = 0.f;
    int i = i0;
    for (; i + 4 <= i1; i += 4) {
        int2 p0 = perm[i], p1 = perm[i + 1], p2 = perm[i + 2], p3 = perm[i + 3];
        float e0[KE], e1[KE], e2[KE], e3[KE];
        load_ea<KE>(ea, p0.y, e0); load_ea<KE>(ea, p1.y, e1);
        load_ea<KE>(ea, p2.y, e2); load_ea<KE>(ea, p3.y, e3);
        float l0 = base + as_[p0.x * 4 + h];
        float l1 = base + as_[p1.x * 4 + h];
        float l2 = base + as_[p2.x * 4 + h];
        float l3 = base + as_[p3.x * 4 + h];
        float4 v0 = *reinterpret_cast<const float4*>(&hs[(size_t)p0.x * 128 + lane * 4]);
        float4 v1 = *reinterpret_cast<const float4*>(&hs[(size_t)p1.x * 128 + lane * 4]);
        float4 v2 = *reinterpret_cast<const float4*>(&hs[(size_t)p2.x * 128 + lane * 4]);
        float4 v3 = *reinterpret_cast<const float4*>(&hs[(size_t)p3.x * 128 + lane * 4]);
        #pragma unroll
        for (int k = 0; k < KE; ++k) {
            l0 += e0[k] * Pk[k]; l1 += e1[k] * Pk[k];
            l2 += e2[k] * Pk[k]; l3 += e3[k] * Pk[k];
        }
        float w0 = expf(lrelu(l0)), w1 = expf(lrelu(l1));
        float w2 = expf(lrelu(l2)), w3 = expf(lrelu(l3));
        ax += v0.x * w0 + v1.x * w1 + v2.x * w2 + v3.x * w3;
        ay += v0.y * w0 + v1.y * w1 + v2.y * w2 + v3.y * w3;
        az += v0.z * w0 + v1.z * w1 + v2.z * w2 + v3.z * w3;
        aw += v0.w * w0 + v1.w * w1 + v2.w * w2 + v3.w * w3;
        den += w0 + w1 + w2 + w3;
    }
    for (; i < i1; ++i) {
        int2 p = perm[i];
        float ev[KE];
        load_ea<KE>(ea, p.y, ev);
        float l = base + as_[p.x * 4 + h];
        #pragma unroll
        for (int k = 0; k < KE; ++k) l += ev[k] * Pk[k];
        float w = expf(lrelu(l));
        float4 v = *reinterpret_cast<const float4*>(&hs[(size_t)p.x * 128 + lane * 4]);
        ax += v.x * w; ay += v.y * w; az += v.z * w; aw += v.w * w;
        den += w;
    }
    float4 b4 = *reinterpret_cast<const float4*>(&bias[lane * 4]);
    float r = 1.f / (den + 1e-16f);
    float4 o = make_float4(fmaxf(ax * r + b4.x, 0.f), fmaxf(ay * r + b4.y, 0.f),
                           fmaxf(az * r + b4.z, 0.f), fmaxf(aw * r + b4.w, 0.f));
    *reinterpret_cast<float4*>(&tasks[(size_t)d * 256 + cbase + lane * 4]) = o;
}

// CSR gather conv3 with recompute: 32 lanes/dst, per-head denominators, unroll x2,
// self-loop (mean edge-attr) message, head-mean, +b3, relu fused. Writes d_out once.
__global__ __launch_bounds__(256) void k_gather_c3(const int* __restrict__ rp,
                                                   const int2* __restrict__ perm,
                                                   const float* __restrict__ as3,
                                                   const float* __restrict__ ad3,
                                                   const float* __restrict__ P3,
                                                   const float* __restrict__ ea,
                                                   const float* __restrict__ hs,
                                                   const float* __restrict__ b3,
                                                   float* __restrict__ out) {
    int tid = threadIdx.x;
    int d = blockIdx.x * 8 + (tid >> 5);
    int c = tid & 31;
    float P3v[16];
    #pragma unroll
    for (int i = 0; i < 16; ++i) P3v[i] = P3[i];
    float4 ad4 = *reinterpret_cast<const float4*>(&ad3[d * 4]);
    float adv[4] = {ad4.x, ad4.y, ad4.z, ad4.w};
    int i0 = rp[d], i1 = rp[d + 1];
    float acc[4] = {0.f, 0.f, 0.f, 0.f};
    float den[4] = {0.f, 0.f, 0.f, 0.f};
    float aes[4] = {0.f, 0.f, 0.f, 0.f};
    int i = i0;
    for (; i + 2 <= i1; i += 2) {
        int2 p0 = perm[i], p1 = perm[i + 1];
        float4 s0 = *reinterpret_cast<const float4*>(&as3[(size_t)p0.x * 4]);
        float4 s1 = *reinterpret_cast<const float4*>(&as3[(size_t)p1.x * 4]);
        float4 q0 = *reinterpret_cast<const float4*>(&ea[(size_t)p0.y * 4]);
        float4 q1 = *reinterpret_cast<const float4*>(&ea[(size_t)p1.y * 4]);
        const float* h0 = hs + (size_t)p0.x * 128 + c;
        const float* h1 = hs + (size_t)p1.x * 128 + c;
        float s0v[4] = {s0.x, s0.y, s0.z, s0.w};
        float s1v[4] = {s1.x, s1.y, s1.z, s1.w};
        #pragma unroll
        for (int hh = 0; hh < 4; ++hh) {
            float ae0 = q0.x * P3v[hh] + q0.y * P3v[4 + hh] + q0.z * P3v[8 + hh] + q0.w * P3v[12 + hh];
            float ae1 = q1.x * P3v[hh] + q1.y * P3v[4 + hh] + q1.z * P3v[8 + hh] + q1.w * P3v[12 + hh];
            float x0 = expf(lrelu(s0v[hh] + adv[hh] + ae0));
            float x1 = expf(lrelu(s1v[hh] + adv[hh] + ae1));
            acc[hh] += x0 * h0[hh * 32] + x1 * h1[hh * 32];
            den[hh] += x0 + x1;
            aes[hh] += ae0 + ae1;
        }
    }
    for (; i < i1; ++i) {
        int2 p = perm[i];
        float4 s0 = *reinterpret_cast<const float4*>(&as3[(size_t)p.x * 4]);
        float4 q0 = *reinterpret_cast<const float4*>(&ea[(size_t)p.y * 4]);
        const float* h0 = hs + (size_t)p.x * 128 + c;
        float s0v[4] = {s0.x, s0.y, s0.z, s0.w};
        #pragma unroll
        for (int hh = 0; hh < 4; ++hh) {
            float ae0 = q0.x * P3v[hh] + q0.y * P3v[4 + hh] + q0.z * P3v[8 + hh] + q0.w * P3v[12 + hh];
            float x0 = expf(lrelu(s0v[hh] + adv[hh] + ae0));
            acc[hh] += x0 * h0[hh * 32];
            den[hh] += x0;
            aes[hh] += ae0;
        }
    }
    float inv = 1.f / fmaxf((float)(i1 - i0), 1.f);
    float4 sd = *reinterpret_cast<const float4*>(&as3[(size_t)d * 4]);
    float sdv[4] = {sd.x, sd.y, sd.z, sd.w};
    const float* hd = hs + (size_t)d * 128 + c;
    float o = 0.f;
    #pragma unroll
    for (int hh = 0; hh < 4; ++hh) {
        float m = aes[hh] * inv;
        float exl = expf(lrelu(sdv[hh] + adv[hh] + m));
        float a = acc[hh] + exl * hd[hh * 32];
        o += a / (den[hh] + exl + 1e-16f);
    }
    o = 0.25f * o + b3[c];
    out[(size_t)d * 32 + c] = o > 0.f ? o : 0.f;
}

// hs3 = tasks[50000,256] @ W3[256,128] via bf16 split MFMA (Ah*Bh + Ah*Bl + Al*Bh)
__global__ __launch_bounds__(256, 2) void k_gemm_mfma(const float* __restrict__ T,
                                                      const unsigned short* __restrict__ w3hT,
                                                      const unsigned short* __restrict__ w3lT,
                                                      float* __restrict__ outp) {
    __shared__ uint4 sB[2][2048];      // [hi/lo][128 cols x 16 chunks], 64 KiB
    int tid = threadIdx.x;
    int lane = tid & 63;
    int wid = tid >> 6;
    int arow = lane & 15;
    int kgrp = lane >> 4;
    int s0 = blockIdx.x * 8 + wid * 2;
    int ss0 = s0 < 3125 ? s0 : 3124;
    int ss1 = (s0 + 1) < 3125 ? (s0 + 1) : 3124;
    const uint4* w3h4 = reinterpret_cast<const uint4*>(w3hT);
    const uint4* w3l4 = reinterpret_cast<const uint4*>(w3lT);

    v4f acc[2][8];
    #pragma unroll
    for (int sp = 0; sp < 2; ++sp)
        #pragma unroll
        for (int nt = 0; nt < 8; ++nt) acc[sp][nt] = (v4f)0.f;

    #pragma unroll
    for (int kt = 0; kt < 2; ++kt) {
        __syncthreads();
        float4 a0[8], a1[8];
        const float* Ta0 = T + (size_t)(ss0 * 16 + arow) * 256 + kt * 128 + kgrp * 8;
        const float* Ta1 = T + (size_t)(ss1 * 16 + arow) * 256 + kt * 128 + kgrp * 8;
        #pragma unroll
        for (int kc = 0; kc < 4; ++kc) {
            a0[kc * 2]     = *reinterpret_cast<const float4*>(Ta0 + kc * 32);
            a0[kc * 2 + 1] = *reinterpret_cast<const float4*>(Ta0 + kc * 32 + 4);
            a1[kc * 2]     = *reinterpret_cast<const float4*>(Ta1 + kc * 32);
            a1[kc * 2 + 1] = *reinterpret_cast<const float4*>(Ta1 + kc * 32 + 4);
        }
        #pragma unroll
        for (int it = 0; it < 8; ++it) {
            int c = it * 256 + tid;
            int n = c >> 4, ch = c & 15;
            int gi = n * 32 + kt * 16 + ch;
            int li = n * 16 + (ch ^ (n & 7));
            sB[0][li] = w3h4[gi];
            sB[1][li] = w3l4[gi];
        }
        __syncthreads();
        #pragma unroll
        for (int kc = 0; kc < 4; ++kc) {
            v8s ah0, al0, ah1, al1;
            cvt_split(a0[kc * 2], a0[kc * 2 + 1], ah0, al0);
            cvt_split(a1[kc * 2], a1[kc * 2 + 1], ah1, al1);
            #pragma unroll
            for (int nt = 0; nt < 8; ++nt) {
                int col = nt * 16 + arow;
                int ch = kc * 4 + kgrp;
                int li = col * 16 + (ch ^ (col & 7));
                v8s bh = *reinterpret_cast<const v8s*>(&sB[0][li]);
                v8s bl = *reinterpret_cast<const v8s*>(&sB[1][li]);
                acc[0][nt] = __builtin_amdgcn_mfma_f32_16x16x32_bf16(ah0, bh, acc[0][nt], 0, 0, 0);
                acc[0][nt] = __builtin_amdgcn_mfma_f32_16x16x32_bf16(ah0, bl, acc[0][nt], 0, 0, 0);
                acc[0][nt] = __builtin_amdgcn_mfma_f32_16x16x32_bf16(al0, bh, acc[0][nt], 0, 0, 0);
                acc[1][nt] = __builtin_amdgcn_mfma_f32_16x16x32_bf16(ah1, bh, acc[1][nt], 0, 0, 0);
                acc[1][nt] = __builtin_amdgcn_mfma_f32_16x16x32_bf16(ah1, bl, acc[1][nt], 0, 0, 0);
                acc[1][nt] = __builtin_amdgcn_mfma_f32_16x16x32_bf16(al1, bh, acc[1][nt], 0, 0, 0);
            }
        }
    }
    if (s0 < 3125) {
        #pragma unroll
        for (int nt = 0; nt < 8; ++nt)
            #pragma unroll
            for (int i = 0; i < 4; ++i)
                outp[(size_t)(s0 * 16 + kgrp * 4 + i) * 128 + nt * 16 + arow] = acc[0][nt][i];
    }
    if (s0 + 1 < 3125) {
        #pragma unroll
        for (int nt = 0; nt < 8; ++nt)
            #pragma unroll
            for (int i = 0; i < 4; ++i)
                outp[(size_t)((s0 + 1) * 16 + kgrp * 4 + i) * 128 + nt * 16 + arow] = acc[1][nt][i];
    }
}

extern "C" void kernel_launch(void* const* d_in, const int* in_sizes, int n_in,
                              void* d_out, int out_size, void* d_ws, size_t ws_size,
                              hipStream_t stream) {
    const float* x_data  = (const float*)d_in[0];
    const float* x_tasks = (const float*)d_in[1];
    const float* x_dev   = (const float*)d_in[2];
    const int*   ei_dt   = (const int*)d_in[3];
    const float* ea_dt   = (const float*)d_in[4];
    const int*   ei_vt   = (const int*)d_in[5];
    const float* ea_vt   = (const float*)d_in[6];
    const int*   ei_tt   = (const int*)d_in[7];
    const float* ea_tt   = (const float*)d_in[8];
    const float* Ws1 = (const float*)d_in[9];  const float* Wd1 = (const float*)d_in[10];
    const float* We1 = (const float*)d_in[11]; const float* As1 = (const float*)d_in[12];
    const float* Ad1 = (const float*)d_in[13]; const float* Ae1 = (const float*)d_in[14];
    const float* b1  = (const float*)d_in[15];
    const float* Ws2 = (const float*)d_in[16]; const float* Wd2 = (const float*)d_in[17];
    const float* We2 = (const float*)d_in[18]; const float* As2 = (const float*)d_in[19];
    const float* Ad2 = (const float*)d_in[20]; const float* Ae2 = (const float*)d_in[21];
    const float* b2  = (const float*)d_in[22];
    const float* W3  = (const float*)d_in[23]; const float* We3 = (const float*)d_in[24];
    const float* As3 = (const float*)d_in[25]; const float* Ad3 = (const float*)d_in[26];
    const float* Ae3 = (const float*)d_in[27]; const float* b3  = (const float*)d_in[28];

    if (ws_size < WS_TOTAL * sizeof(float)) return;

    float* w = (float*)d_ws;
    float* tasks = w + OFF_TASKS;
    float* hs    = w + OFF_HS;                 // hs1 (conv1) then hs3 (conv3)
    int*   rank  = (int*)(w + OFF_RANK);
    int2*  perm1 = (int2*)(w + OFF_PERM1);
    int2*  perm2 = (int2*)(w + OFF_PERM2);
    int2*  perm3 = (int2*)(w + OFF_PERM3);
    int*   deg   = (int*)(w + OFF_DEG);
    int*   rp    = (int*)(w + OFF_RP);
    int*   bsum  = (int*)(w + OFF_BSUM);
    unsigned short* w3hT = (unsigned short*)(w + OFF_W3HT);
    unsigned short* w3lT = (unsigned short*)(w + OFF_W3LT);
    float* as1 = w + OFF_AS1;
    float* ad1 = w + OFF_AD1; float* as3 = w + OFF_AD1;   // as3 aliases ad1
    float* ad2 = w + OFF_AD2; float* ad3 = w + OFF_AD2;   // ad3 aliases ad2
    float* hs2 = w + OFF_HS2; float* as2 = w + OFF_AS2;
    float* Qs1 = w + OFF_QS1; float* Qd1 = w + OFF_QD1; float* P1 = w + OFF_P1;
    float* Qs2 = w + OFF_QS2; float* Qd2 = w + OFF_QD2; float* P2 = w + OFF_P2;
    float* P3  = w + OFF_P3;
    float* out = (float*)d_out;

    dim3 B(256);
    #define GRID(n) dim3((unsigned)(((n) + 255) / 256))

    // CSR prep: zero degrees, histogram(+rank), hierarchical scan, atomic-free permute
    hipMemsetAsync(deg, 0, 3 * NT * sizeof(int), stream);
    k_proj_small<<<1, 320, 0, stream>>>(Ws1, As1, Wd1, Ad1, We1, Ae1,
                                        Ws2, As2, Wd2, Ad2, We2, Ae2, We3, Ae3,
                                        Qs1, Qd1, P1, Qs2, Qd2, P2, P3);
    k_w3split<<<GRID(256 * 128), B, 0, stream>>>(W3, w3hT, w3lT);
    k_hist<<<GRID(EDT + EVT + ETT), B, 0, stream>>>(ei_dt, ei_vt, ei_tt, deg, rank);
    k_scan_part<<<dim3(3 * SCAN_NB), B, 0, stream>>>(deg, bsum);
    k_scan_bsum<<<1, 64, 0, stream>>>(bsum, rp);
    k_scan_final<<<dim3(3 * SCAN_NB), B, 0, stream>>>(deg, bsum, rp);
    k_permute<<<GRID(EDT + EVT + ETT), B, 0, stream>>>(ei_dt, ei_vt, ei_tt, rank, rp,
                                                       perm1, perm2, perm3);

    // conv1 + conv2 inputs
    k_linproj<<<GRID(NDAT * 128), B, 0, stream>>>(x_data, Ws1, hs, NDAT, 8);
    k_alpha<<<GRID(NDAT * 4), B, 0, stream>>>(x_data, Qs1, as1, NDAT, 8);
    k_alpha2<<<GRID(NT * 4), B, 0, stream>>>(x_tasks, Qd1, Qd2, ad1, ad2, NT, 16);
    k_linproj<<<GRID(NDEV * 128), B, 0, stream>>>(x_dev, Ws2, hs2, NDEV, 8);
    k_alpha<<<GRID(NDEV * 4), B, 0, stream>>>(x_dev, Qs2, as2, NDEV, 8);
    // gathers with attention recompute (bias+relu fused)
    k_gather12<8><<<dim3(NT / 8), B, 0, stream>>>(rp, perm1, as1, ad1, P1, ea_dt,
                                                  hs, b1, tasks, 0);
    k_gather12<6><<<dim3(NT / 8), B, 0, stream>>>(rp + (NT + 1), perm2, as2, ad2, P2, ea_vt,
                                                  hs2, b2, tasks, 128);

    // conv3: tasks -> tasks
    k_gemm_mfma<<<dim3(391), dim3(256), 0, stream>>>(tasks, w3hT, w3lT, hs);
    k_alpha_from_h2<<<GRID(NT * 4), B, 0, stream>>>(hs, As3, Ad3, as3, ad3, NT);
    k_gather_c3<<<dim3(NT / 8), B, 0, stream>>>(rp + 2 * (NT + 1), perm3, as3, ad3, P3, ea_tt,
                                                hs, b3, out);
    #undef GRID
}